// Round 1
// baseline (2703.469 us; speedup 1.0000x reference)
//
#include <hip/hip_runtime.h>
#include <hip/hip_bf16.h>
#include <math.h>

typedef __hip_bfloat16 bf16;

#define NN 16384
#define EE 65536
#define BB 512

__device__ __forceinline__ float lrelu_f(float x){ return x >= 0.f ? x : 0.01f*x; }

// ---------------- GEMM: C[M,N] = act(A[M,K] @ W[K,N] + bias) ----------------
// ACT: 0 = none, 1 = lrelu, 2 = BN+lrelu  (v*bnscale*gamma[n]+beta[n] then lrelu)
// M, N multiples of 64; K arbitrary (guarded). All col-offset folding done by caller
// via pre-offset W/bias/C pointers + ldw/ldc strides.
template<typename CT, int ACT>
__global__ __launch_bounds__(256)
void gemm_kernel(const float* __restrict__ A, int lda,
                 const float* __restrict__ W, int ldw,
                 const float* __restrict__ bias,
                 const float* __restrict__ gamma,
                 const float* __restrict__ beta,
                 float bnscale,
                 CT* __restrict__ C, int ldc,
                 int M, int N, int K)
{
    __shared__ float As[16][68];   // As[k][m], +4 pad keeps 16B alignment for b128
    __shared__ float Bs[16][68];   // Bs[k][n]
    const int tid = threadIdx.x;
    const int tx = tid & 15;
    const int ty = tid >> 4;
    const int m0 = blockIdx.y * 64;
    const int n0 = blockIdx.x * 64;
    float acc[4][4];
    #pragma unroll
    for (int i=0;i<4;i++)
        #pragma unroll
        for (int j=0;j<4;j++) acc[i][j]=0.f;

    for (int k0=0; k0<K; k0+=16) {
        #pragma unroll
        for (int i=0;i<4;i++){
            int idx = tid + i*256;
            int r = idx >> 4, c = idx & 15;
            int kk = k0 + c;
            As[c][r] = (kk < K) ? A[(size_t)(m0+r)*lda + kk] : 0.f;
        }
        #pragma unroll
        for (int i=0;i<4;i++){
            int idx = tid + i*256;
            int r = idx >> 6, c = idx & 63;
            int kk = k0 + r;
            Bs[r][c] = (kk < K) ? W[(size_t)kk*ldw + n0 + c] : 0.f;
        }
        __syncthreads();
        #pragma unroll
        for (int kk=0;kk<16;kk++){
            float a[4], b[4];
            #pragma unroll
            for (int i=0;i<4;i++) a[i] = As[kk][ty*4+i];
            #pragma unroll
            for (int j=0;j<4;j++) b[j] = Bs[kk][tx*4+j];
            #pragma unroll
            for (int i=0;i<4;i++)
                #pragma unroll
                for (int j=0;j<4;j++) acc[i][j] += a[i]*b[j];
        }
        __syncthreads();
    }
    #pragma unroll
    for (int i=0;i<4;i++){
        int m = m0 + ty*4 + i;
        #pragma unroll
        for (int j=0;j<4;j++){
            int n = n0 + tx*4 + j;
            float vv = acc[i][j] + bias[n];
            if (ACT==1) vv = lrelu_f(vv);
            if (ACT==2) { vv = vv*bnscale*gamma[n] + beta[n]; vv = lrelu_f(vv); }
            C[(size_t)m*ldc + n] = (CT)vv;
        }
    }
}

// ---------------- CSR build ----------------
__global__ void hist_kernel(const int* __restrict__ ei, int* __restrict__ cnt){
    int e = blockIdx.x*256 + threadIdx.x;
    atomicAdd(&cnt[ei[EE + e]], 1);   // dst = ei[1][e]
}

__global__ __launch_bounds__(1024)
void scan_kernel(const int* __restrict__ hist, int* __restrict__ rowptr){
    __shared__ int sums[1024];
    const int t = threadIdx.x;
    const int base = t*16;
    int loc[16]; int s = 0;
    #pragma unroll
    for (int i=0;i<16;i++){ loc[i]=s; s += hist[base+i]; }
    sums[t] = s; __syncthreads();
    for (int o=1;o<1024;o<<=1){
        int v = (t>=o) ? sums[t-o] : 0;
        __syncthreads();
        sums[t] += v;
        __syncthreads();
    }
    int pref = (t>0) ? sums[t-1] : 0;
    #pragma unroll
    for (int i=0;i<16;i++) rowptr[base+i] = pref + loc[i];
    if (t==1023) rowptr[NN] = sums[1023];
}

__global__ void scatter_kernel(const int* __restrict__ ei, const int* __restrict__ rowptr,
                               int* __restrict__ cnt, int* __restrict__ se){
    int e = blockIdx.x*256 + threadIdx.x;
    int d = ei[EE + e];
    int pos = rowptr[d] + atomicAdd(&cnt[d], 1);
    se[pos] = e;
}

__global__ void range_kernel(const int* __restrict__ bt, int* __restrict__ bs, int* __restrict__ be){
    int n = blockIdx.x*256 + threadIdx.x;
    int b = bt[n];
    if (n==0     || bt[n-1]!=b) bs[b] = n;
    if (n==NN-1  || bt[n+1]!=b) be[b] = n+1;
}

// ---------------- Attention: one wave per (dst node, head) ----------------
// hout pre-filled with skip (x@ws+bs); writes lrelu(skip + agg) in place.
template<int D, int H>
__global__ __launch_bounds__(256)
void attn_kernel(const bf16* __restrict__ q, const bf16* __restrict__ k,
                 const bf16* __restrict__ v, float* __restrict__ hout,
                 const int* __restrict__ rowptr, const int* __restrict__ se,
                 const int* __restrict__ ei)
{
    constexpr int PER = D / 64;
    const int lane = threadIdx.x & 63;
    const int gw = blockIdx.x * 4 + (threadIdx.x >> 6);
    const int n = gw / H;
    const int h = gw % H;
    const float scale = 1.0f / sqrtf((float)D);

    const bf16* qp = q + (size_t)n*(H*D) + h*D + lane;
    float qr[PER];
    #pragma unroll
    for (int i=0;i<PER;i++) qr[i] = (float)qp[i*64];

    const int e0 = rowptr[n], e1 = rowptr[n+1];
    float m = -INFINITY, z = 0.f;
    for (int p=e0; p<e1; p++){
        const int src = ei[se[p]];
        const bf16* kp = k + (size_t)src*(H*D) + h*D + lane;
        float dot = 0.f;
        #pragma unroll
        for (int i=0;i<PER;i++) dot += qr[i] * (float)kp[i*64];
        #pragma unroll
        for (int o=32;o;o>>=1) dot += __shfl_xor(dot, o, 64);
        dot *= scale;
        if (dot > m){ z *= expf(m - dot); m = dot; }
        z += expf(dot - m);
    }
    const float invz = 1.0f / (z + 1e-16f);

    float acc[PER];
    #pragma unroll
    for (int i=0;i<PER;i++) acc[i] = 0.f;
    for (int p=e0; p<e1; p++){
        const int src = ei[se[p]];
        const bf16* kp = k + (size_t)src*(H*D) + h*D + lane;
        float dot = 0.f;
        #pragma unroll
        for (int i=0;i<PER;i++) dot += qr[i] * (float)kp[i*64];
        #pragma unroll
        for (int o=32;o;o>>=1) dot += __shfl_xor(dot, o, 64);
        dot *= scale;
        const float alpha = expf(dot - m) * invz;
        const bf16* vp = v + (size_t)src*(H*D) + h*D + lane;
        #pragma unroll
        for (int i=0;i<PER;i++) acc[i] += alpha * (float)vp[i*64];
    }
    float* op = hout + (size_t)n*(H*D) + h*D + lane;
    #pragma unroll
    for (int i=0;i<PER;i++) op[i*64] = lrelu_f(op[i*64] + acc[i]);
}

// ---------------- segment-max pool over nodes of each graph ----------------
__global__ __launch_bounds__(256)
void pool_kernel(const float* __restrict__ h, int ldh, int cols,
                 const int* __restrict__ bs, const int* __restrict__ be,
                 float* __restrict__ g, int ldg, int gc0)
{
    int c = blockIdx.x*256 + threadIdx.x;
    int b = blockIdx.y;
    if (c >= cols) return;
    float m = -INFINITY;
    for (int n = bs[b]; n < be[b]; n++) m = fmaxf(m, h[(size_t)n*ldh + c]);
    g[(size_t)b*ldg + gc0 + c] = (m == -INFINITY) ? 0.f : m;
}

// ---------------- row L2 normalize ----------------
__global__ __launch_bounds__(256)
void l2n_kernel(const float* __restrict__ in, float* __restrict__ outp,
                int cols, int ldi, int ldo)
{
    __shared__ float red[4];
    const int r = blockIdx.x;
    const int t = threadIdx.x;
    const float* ip = in + (size_t)r*ldi;
    float* op = outp + (size_t)r*ldo;
    float s = 0.f;
    for (int c=t; c<cols; c+=256){ float v = ip[c]; s += v*v; }
    #pragma unroll
    for (int o=32;o;o>>=1) s += __shfl_xor(s, o, 64);
    if ((t & 63) == 0) red[t>>6] = s;
    __syncthreads();
    float tot = red[0]+red[1]+red[2]+red[3];
    float inv = 1.0f / fmaxf(sqrtf(tot), 1e-12f);
    for (int c=t; c<cols; c+=256) op[c] = ip[c]*inv;
}

// ---------------- final 256->1 dot + sigmoid ----------------
__global__ __launch_bounds__(64)
void final_kernel(const float* __restrict__ f2, const float* __restrict__ w,
                  const float* __restrict__ b, float* __restrict__ outp)
{
    const int r = blockIdx.x;
    const int lane = threadIdx.x;
    const float* fp = f2 + (size_t)r*256;
    float s = 0.f;
    for (int c=lane; c<256; c+=64) s += fp[c]*w[c];
    #pragma unroll
    for (int o=32;o;o>>=1) s += __shfl_xor(s, o, 64);
    if (lane==0) outp[r] = 1.0f/(1.0f + expf(-(s + b[0])));
}

extern "C" void kernel_launch(void* const* d_in, const int* in_sizes, int n_in,
                              void* d_out, int out_size, void* d_ws, size_t ws_size,
                              hipStream_t stream)
{
    const float* x1  = (const float*)d_in[0];
    const int*   ei1 = (const int*)  d_in[1];
    const int*   bt1 = (const int*)  d_in[2];
    const float* x2  = (const float*)d_in[3];
    const int*   ei2 = (const int*)  d_in[4];
    const int*   bt2 = (const int*)  d_in[5];
    const float* cell= (const float*)d_in[6];
    const float* wq1=(const float*)d_in[7];  const float* bq1=(const float*)d_in[8];
    const float* wk1=(const float*)d_in[9];  const float* bk1=(const float*)d_in[10];
    const float* wv1=(const float*)d_in[11]; const float* bv1=(const float*)d_in[12];
    const float* ws1=(const float*)d_in[13]; const float* bs1=(const float*)d_in[14];
    const float* wq2=(const float*)d_in[15]; const float* bq2=(const float*)d_in[16];
    const float* wk2=(const float*)d_in[17]; const float* bk2=(const float*)d_in[18];
    const float* wv2=(const float*)d_in[19]; const float* bv2=(const float*)d_in[20];
    const float* ws2=(const float*)d_in[21]; const float* bs2=(const float*)d_in[22];
    const float* wg1=(const float*)d_in[23]; const float* bg1=(const float*)d_in[24];
    const float* wg2=(const float*)d_in[25]; const float* bg2=(const float*)d_in[26];
    const float* wr1=(const float*)d_in[27]; const float* br1=(const float*)d_in[28];
    const float* wr2=(const float*)d_in[29]; const float* br2=(const float*)d_in[30];
    const float* wr3=(const float*)d_in[31]; const float* br3=(const float*)d_in[32];
    const float* wf1=(const float*)d_in[33]; const float* bf1=(const float*)d_in[34];
    const float* gbn1=(const float*)d_in[35];const float* bbn1=(const float*)d_in[36];
    const float* wf2=(const float*)d_in[37]; const float* bf2=(const float*)d_in[38];
    const float* gbn2=(const float*)d_in[39];const float* bbn2=(const float*)d_in[40];
    const float* wf3=(const float*)d_in[41]; const float* bf3=(const float*)d_in[42];
    float* outp = (float*)d_out;
    (void)in_sizes; (void)n_in; (void)out_size; (void)ws_size;

    const float BNS = 1.0f / sqrtf(1.0f + 1e-5f);

    // ---- workspace arena (~111 MB peak) ----
    char* basep = (char*)d_ws;
    size_t off = 0;
    auto alloc = [&](size_t nbytes)->char* {
        char* p = basep + off;
        off += (nbytes + 255) & ~(size_t)255;
        return p;
    };
    float* xc   = (float*)alloc((size_t)BB*384*4);     // concat target [B,384]
    int* rowptr = (int*)  alloc((size_t)(NN+1)*4);
    int* cnt    = (int*)  alloc((size_t)NN*4);
    int* se     = (int*)  alloc((size_t)EE*4);
    int* bstart = (int*)  alloc((size_t)BB*4);
    int* bend   = (int*)  alloc((size_t)BB*4);
    bf16* qb    = (bf16*) alloc((size_t)NN*512*2);     // holds q1[N,256] or q2h[N,512]
    bf16* kb    = (bf16*) alloc((size_t)NN*512*2);
    bf16* vb    = (bf16*) alloc((size_t)NN*512*2);
    float* h1   = (float*)alloc((size_t)NN*256*4);
    float* h2h  = (float*)alloc((size_t)NN*512*4);
    float* g    = (float*)alloc((size_t)BB*1024*4);
    float* gh   = (float*)alloc((size_t)BB*512*4);
    float* cn   = (float*)alloc((size_t)BB*954*4);
    float* c1   = (float*)alloc((size_t)BB*512*4);
    float* c2   = (float*)alloc((size_t)BB*256*4);
    float* f1   = (float*)alloc((size_t)BB*512*4);
    float* f2   = (float*)alloc((size_t)BB*256*4);

    for (int br=0; br<2; br++){
        const float* x  = br ? x2  : x1;
        const int*   ei = br ? ei2 : ei1;
        const int*   bt = br ? bt2 : bt1;
        float* gout = xc + br*128;

        // CSR of incoming edges (shared by both conv layers)
        hipMemsetAsync(cnt, 0, (size_t)NN*4, stream);
        hist_kernel<<<EE/256,256,0,stream>>>(ei, cnt);
        scan_kernel<<<1,1024,0,stream>>>(cnt, rowptr);
        hipMemsetAsync(cnt, 0, (size_t)NN*4, stream);
        scatter_kernel<<<EE/256,256,0,stream>>>(ei, rowptr, cnt, se);
        hipMemsetAsync(bstart, 0, (size_t)BB*4, stream);
        hipMemsetAsync(bend,   0, (size_t)BB*4, stream);
        range_kernel<<<NN/256,256,0,stream>>>(bt, bstart, bend);

        // ---- layer 1: 78 -> 2x128 ----
        gemm_kernel<bf16,0><<<dim3(4,NN/64),256,0,stream>>>(x,78, wq1,256, bq1, nullptr,nullptr,1.f, qb,256, NN,256,78);
        gemm_kernel<bf16,0><<<dim3(4,NN/64),256,0,stream>>>(x,78, wk1,256, bk1, nullptr,nullptr,1.f, kb,256, NN,256,78);
        gemm_kernel<bf16,0><<<dim3(4,NN/64),256,0,stream>>>(x,78, wv1,256, bv1, nullptr,nullptr,1.f, vb,256, NN,256,78);
        gemm_kernel<float,0><<<dim3(4,NN/64),256,0,stream>>>(x,78, ws1,256, bs1, nullptr,nullptr,1.f, h1,256, NN,256,78);
        attn_kernel<128,2><<<NN*2/4,256,0,stream>>>(qb,kb,vb,h1,rowptr,se,ei);

        // ---- layer 2: 256 -> 2x512, one head at a time (workspace economy) ----
        for (int h=0; h<2; h++){
            const int c0 = h*512;
            gemm_kernel<bf16,0><<<dim3(8,NN/64),256,0,stream>>>(h1,256, wq2+c0,1024, bq2+c0, nullptr,nullptr,1.f, qb,512, NN,512,256);
            gemm_kernel<bf16,0><<<dim3(8,NN/64),256,0,stream>>>(h1,256, wk2+c0,1024, bk2+c0, nullptr,nullptr,1.f, kb,512, NN,512,256);
            gemm_kernel<bf16,0><<<dim3(8,NN/64),256,0,stream>>>(h1,256, wv2+c0,1024, bv2+c0, nullptr,nullptr,1.f, vb,512, NN,512,256);
            gemm_kernel<float,0><<<dim3(8,NN/64),256,0,stream>>>(h1,256, ws2+c0,1024, bs2+c0, nullptr,nullptr,1.f, h2h,512, NN,512,256);
            attn_kernel<512,1><<<NN/4,256,0,stream>>>(qb,kb,vb,h2h,rowptr,se,ei);
            pool_kernel<<<dim3(2,BB),256,0,stream>>>(h2h,512,512,bstart,bend,g,1024,c0);
        }

        // ---- graph head: 1024 -> 512 (lrelu) -> 128, then row-l2n ----
        gemm_kernel<float,1><<<dim3(8,8),256,0,stream>>>(g,1024, wg1,512, bg1, nullptr,nullptr,1.f, gh,512, BB,512,1024);
        gemm_kernel<float,0><<<dim3(2,8),256,0,stream>>>(gh,512, wg2,128, bg2, nullptr,nullptr,1.f, gout,384, BB,128,512);
        l2n_kernel<<<BB,256,0,stream>>>(gout, gout, 128, 384, 384);
    }

    // ---- cell branch ----
    l2n_kernel<<<BB,256,0,stream>>>(cell, cn, 954, 954, 954);
    gemm_kernel<float,1><<<dim3(8,8),256,0,stream>>>(cn,954, wr1,512, br1, nullptr,nullptr,1.f, c1,512, BB,512,954);
    gemm_kernel<float,1><<<dim3(4,8),256,0,stream>>>(c1,512, wr2,256, br2, nullptr,nullptr,1.f, c2,256, BB,256,512);
    gemm_kernel<float,0><<<dim3(2,8),256,0,stream>>>(c2,256, wr3,128, br3, nullptr,nullptr,1.f, xc+256,384, BB,128,256);

    // ---- head MLP ----
    l2n_kernel<<<BB,256,0,stream>>>(xc, xc, 384, 384, 384);
    gemm_kernel<float,2><<<dim3(8,8),256,0,stream>>>(xc,384, wf1,512, bf1, gbn1,bbn1,BNS, f1,512, BB,512,384);
    gemm_kernel<float,2><<<dim3(4,8),256,0,stream>>>(f1,512, wf2,256, bf2, gbn2,bbn2,BNS, f2,256, BB,256,512);
    final_kernel<<<BB,64,0,stream>>>(f2, wf3, bf3, outp);
}

// Round 2
// 1477.789 us; speedup vs baseline: 1.8294x; 1.8294x over previous
//
#include <hip/hip_runtime.h>
#include <hip/hip_bf16.h>
#include <math.h>
#include <stdint.h>

typedef __hip_bfloat16 bf16;

#define NN 16384
#define EE 65536
#define BB 512

typedef __attribute__((ext_vector_type(8))) short short8;
typedef __attribute__((ext_vector_type(4))) float floatx4;

__device__ __forceinline__ float lrelu_f(float x){ return x >= 0.f ? x : 0.01f*x; }

// async 16B global->LDS. LDS dest is wave-uniform base; lane i lands at base+16*i.
__device__ __forceinline__ void gl2lds16(const void* g, void* l){
    __builtin_amdgcn_global_load_lds(
        (__attribute__((address_space(1))) unsigned int*)(uintptr_t)g,
        (__attribute__((address_space(3))) unsigned int*)(uintptr_t)l, 16, 0, 0);
}

// ================= MFMA bf16 GEMM: C[m,n] = A[m,:K] @ W[:,n] + bias[n] =================
// A: bf16 [M, lda] row-major (lda >= K, 16B-aligned rows). Bt: bf16 [N, ldb] N-MAJOR,
// k-contiguous (Bt[n][k] = W[k][n]). C: bf16 [M, ldc]. M,N multiples of 128; K mult of 32.
__global__ __launch_bounds__(256)
void mfma_gemm(const bf16* __restrict__ A, int lda,
               const bf16* __restrict__ Bt, int ldb,
               const float* __restrict__ bias,
               bf16* __restrict__ C, int ldc, int K)
{
    __shared__ bf16 As[128*32];   // As[r][k] r=0..127, k=0..31
    __shared__ bf16 Bs[128*32];   // Bs[n][k]
    const int tid  = threadIdx.x;
    const int wave = tid >> 6;
    const int lane = tid & 63;
    const int wm = (wave & 1) * 64;
    const int wn = (wave >> 1) * 64;
    const int m0 = blockIdx.y * 128;
    const int n0 = blockIdx.x * 128;

    const int srow = lane >> 2;        // 0..15 within a 16-row staging chunk
    const int scol = (lane & 3) * 8;   // k-offset (8 bf16 = 16B)
    const int arow = lane & 15;
    const int aq   = (lane >> 4) * 8;

    floatx4 acc[4][4];
    #pragma unroll
    for (int i=0;i<4;i++)
        #pragma unroll
        for (int j=0;j<4;j++) acc[i][j] = (floatx4){0.f,0.f,0.f,0.f};

    for (int k0 = 0; k0 < K; k0 += 32) {
        #pragma unroll
        for (int i = 0; i < 2; i++) {
            const int chunk = wave*2 + i;        // 0..7, 16 rows each
            const int r = chunk*16 + srow;
            gl2lds16(A  + (size_t)(m0 + r)*lda + k0 + scol, As + chunk*512);
            gl2lds16(Bt + (size_t)(n0 + r)*ldb + k0 + scol, Bs + chunk*512);
        }
        __syncthreads();   // drains vmcnt -> staged data visible
        short8 af[4], bf_[4];
        #pragma unroll
        for (int i=0;i<4;i++) af[i]  = *(const short8*)(As + (wm + i*16 + arow)*32 + aq);
        #pragma unroll
        for (int j=0;j<4;j++) bf_[j] = *(const short8*)(Bs + (wn + j*16 + arow)*32 + aq);
        #pragma unroll
        for (int i=0;i<4;i++)
            #pragma unroll
            for (int j=0;j<4;j++)
                acc[i][j] = __builtin_amdgcn_mfma_f32_16x16x32_bf16(af[i], bf_[j], acc[i][j], 0,0,0);
        __syncthreads();
    }
    // epilogue: D layout col=lane&15, row=(lane>>4)*4+reg
    const int crow = (lane >> 4) * 4;
    const int ccol = lane & 15;
    #pragma unroll
    for (int j=0;j<4;j++){
        const int n = n0 + wn + j*16 + ccol;
        const float bs = bias[n];
        #pragma unroll
        for (int i=0;i<4;i++){
            const int m = m0 + wm + i*16 + crow;
            #pragma unroll
            for (int r=0;r<4;r++)
                C[(size_t)(m + r)*ldc + n] = (bf16)(acc[i][j][r] + bs);
        }
    }
}

// ================= weight/bias/activation prep =================
__global__ void cvt_x_kernel(const float* __restrict__ x, bf16* __restrict__ xa){
    int i = blockIdx.x*256 + threadIdx.x;          // over NN*96
    int r = i / 96, c = i - r*96;
    xa[i] = (c < 78) ? (bf16)x[(size_t)r*78 + c] : (bf16)0.f;
}

__global__ void prep_w1_kernel(const float* __restrict__ wq, const float* __restrict__ wk,
                               const float* __restrict__ wv, const float* __restrict__ ws,
                               bf16* __restrict__ W1t){
    int i = blockIdx.x*256 + threadIdx.x;          // 1024*96
    int n = i / 96, k = i - n*96;
    const float* w = (n<256)?wq:(n<512)?wk:(n<768)?wv:ws;
    int col = n & 255;
    W1t[i] = (k < 78) ? (bf16)w[(size_t)k*256 + col] : (bf16)0.f;
}

__global__ void prep_b1_kernel(const float* __restrict__ bq, const float* __restrict__ bk,
                               const float* __restrict__ bv, const float* __restrict__ bs,
                               float* __restrict__ b1c){
    int i = blockIdx.x*256 + threadIdx.x;          // 1024
    if (i >= 1024) return;
    const float* b = (i<256)?bq:(i<512)?bk:(i<768)?bv:bs;
    b1c[i] = b[i & 255];
}

// W2t[h][j][k]: j in [0,2048) = q(512)|k(512)|v(512)|s(512) of head h; k in [0,256)
__global__ void prep_w2_kernel(const float* __restrict__ wq, const float* __restrict__ wk,
                               const float* __restrict__ wv, const float* __restrict__ ws,
                               bf16* __restrict__ W2t){
    int i = blockIdx.x*256 + threadIdx.x;          // 2*2048*256
    int k = i & 255;
    int j = (i >> 8) & 2047;
    int h = i >> 19;
    const float* w = (j<512)?wq:(j<1024)?wk:(j<1536)?wv:ws;
    int col = h*512 + (j & 511);
    W2t[i] = (bf16)w[(size_t)k*1024 + col];
}

__global__ void prep_b2_kernel(const float* __restrict__ bq, const float* __restrict__ bk,
                               const float* __restrict__ bv, const float* __restrict__ bs,
                               float* __restrict__ b2c){
    int i = blockIdx.x*256 + threadIdx.x;          // 4096
    if (i >= 4096) return;
    int j = i & 2047, h = i >> 11;
    const float* b = (j<512)?bq:(j<1024)?bk:(j<1536)?bv:bs;
    b2c[i] = b[h*512 + (j & 511)];
}

// ================= small fp32 GEMM (B=512 MLP heads) =================
// ACT: 0 none, 1 lrelu, 2 BN+lrelu
template<int ACT>
__global__ __launch_bounds__(256)
void gemm_kernel(const float* __restrict__ A, int lda,
                 const float* __restrict__ W, int ldw,
                 const float* __restrict__ bias,
                 const float* __restrict__ gamma,
                 const float* __restrict__ beta,
                 float bnscale,
                 float* __restrict__ C, int ldc,
                 int M, int N, int K)
{
    __shared__ float As[16][68];
    __shared__ float Bs[16][68];
    const int tid = threadIdx.x;
    const int tx = tid & 15;
    const int ty = tid >> 4;
    const int m0 = blockIdx.y * 64;
    const int n0 = blockIdx.x * 64;
    float acc[4][4];
    #pragma unroll
    for (int i=0;i<4;i++)
        #pragma unroll
        for (int j=0;j<4;j++) acc[i][j]=0.f;

    for (int k0=0; k0<K; k0+=16) {
        #pragma unroll
        for (int i=0;i<4;i++){
            int idx = tid + i*256;
            int r = idx >> 4, c = idx & 15;
            int kk = k0 + c;
            As[c][r] = (kk < K) ? A[(size_t)(m0+r)*lda + kk] : 0.f;
        }
        #pragma unroll
        for (int i=0;i<4;i++){
            int idx = tid + i*256;
            int r = idx >> 6, c = idx & 63;
            int kk = k0 + r;
            Bs[r][c] = (kk < K) ? W[(size_t)kk*ldw + n0 + c] : 0.f;
        }
        __syncthreads();
        #pragma unroll
        for (int kk=0;kk<16;kk++){
            float a[4], b[4];
            #pragma unroll
            for (int i=0;i<4;i++) a[i] = As[kk][ty*4+i];
            #pragma unroll
            for (int j=0;j<4;j++) b[j] = Bs[kk][tx*4+j];
            #pragma unroll
            for (int i=0;i<4;i++)
                #pragma unroll
                for (int j=0;j<4;j++) acc[i][j] += a[i]*b[j];
        }
        __syncthreads();
    }
    #pragma unroll
    for (int i=0;i<4;i++){
        int m = m0 + ty*4 + i;
        #pragma unroll
        for (int j=0;j<4;j++){
            int n = n0 + tx*4 + j;
            float vv = acc[i][j] + bias[n];
            if (ACT==1) vv = lrelu_f(vv);
            if (ACT==2) { vv = vv*bnscale*gamma[n] + beta[n]; vv = lrelu_f(vv); }
            C[(size_t)m*ldc + n] = vv;
        }
    }
}

// ================= CSR build =================
__global__ void hist_kernel(const int* __restrict__ ei, int* __restrict__ cnt){
    int e = blockIdx.x*256 + threadIdx.x;
    atomicAdd(&cnt[ei[EE + e]], 1);
}

__global__ __launch_bounds__(1024)
void scan_kernel(const int* __restrict__ hist, int* __restrict__ rowptr){
    __shared__ int sums[1024];
    const int t = threadIdx.x;
    const int base = t*16;
    int loc[16]; int s = 0;
    #pragma unroll
    for (int i=0;i<16;i++){ loc[i]=s; s += hist[base+i]; }
    sums[t] = s; __syncthreads();
    for (int o=1;o<1024;o<<=1){
        int v = (t>=o) ? sums[t-o] : 0;
        __syncthreads();
        sums[t] += v;
        __syncthreads();
    }
    int pref = (t>0) ? sums[t-1] : 0;
    #pragma unroll
    for (int i=0;i<16;i++) rowptr[base+i] = pref + loc[i];
    if (t==1023) rowptr[NN] = sums[1023];
}

__global__ void scatter_kernel(const int* __restrict__ ei, const int* __restrict__ rowptr,
                               int* __restrict__ cnt, int* __restrict__ se){
    int e = blockIdx.x*256 + threadIdx.x;
    int d = ei[EE + e];
    int pos = rowptr[d] + atomicAdd(&cnt[d], 1);
    se[pos] = e;
}

__global__ void range_kernel(const int* __restrict__ bt, int* __restrict__ bs, int* __restrict__ be){
    int n = blockIdx.x*256 + threadIdx.x;
    int b = bt[n];
    if (n==0     || bt[n-1]!=b) bs[b] = n;
    if (n==NN-1  || bt[n+1]!=b) be[b] = n+1;
}

// ================= attention: one wave per (dst node, head) =================
// qkvs: bf16 [NN, ld] holding q|k|v|s blocks at col offsets qo/ko/vo/so (+h*D within block).
// out:  bf16 [NN, ldo], col offset oo + h*D.  out = lrelu(s + softmax-agg(v))
template<int D>
__global__ __launch_bounds__(256)
void attn_kernel(const bf16* __restrict__ qkvs, int ld, int qo, int ko, int vo, int so, int H,
                 bf16* __restrict__ hout, int ldo, int oo,
                 const int* __restrict__ rowptr, const int* __restrict__ se,
                 const int* __restrict__ ei)
{
    constexpr int PER = D / 64;
    const int lane = threadIdx.x & 63;
    const int gw = blockIdx.x * 4 + (threadIdx.x >> 6);
    const int n = gw / H;
    const int h = gw - n*H;
    const float scale = rsqrtf((float)D);
    const int hd = h*D + lane;

    const bf16* qp = qkvs + (size_t)n*ld + qo + hd;
    float qr[PER];
    #pragma unroll
    for (int i=0;i<PER;i++) qr[i] = (float)qp[i*64];

    const int e0 = rowptr[n], e1 = rowptr[n+1];
    float m = -INFINITY, z = 0.f;
    for (int p=e0; p<e1; p++){
        const int src = ei[se[p]];
        const bf16* kp = qkvs + (size_t)src*ld + ko + hd;
        float dot = 0.f;
        #pragma unroll
        for (int i=0;i<PER;i++) dot += qr[i] * (float)kp[i*64];
        #pragma unroll
        for (int o=32;o;o>>=1) dot += __shfl_xor(dot, o, 64);
        dot *= scale;
        if (dot > m){ z *= expf(m - dot); m = dot; }
        z += expf(dot - m);
    }
    const float invz = 1.0f / (z + 1e-16f);

    float acc[PER];
    #pragma unroll
    for (int i=0;i<PER;i++) acc[i] = 0.f;
    for (int p=e0; p<e1; p++){
        const int src = ei[se[p]];
        const bf16* kp = qkvs + (size_t)src*ld + ko + hd;
        float dot = 0.f;
        #pragma unroll
        for (int i=0;i<PER;i++) dot += qr[i] * (float)kp[i*64];
        #pragma unroll
        for (int o=32;o;o>>=1) dot += __shfl_xor(dot, o, 64);
        dot *= scale;
        const float alpha = expf(dot - m) * invz;
        const bf16* vp = qkvs + (size_t)src*ld + vo + hd;
        #pragma unroll
        for (int i=0;i<PER;i++) acc[i] += alpha * (float)vp[i*64];
    }
    const bf16* sp = qkvs + (size_t)n*ld + so + hd;
    bf16* op = hout + (size_t)n*ldo + oo + hd;
    #pragma unroll
    for (int i=0;i<PER;i++) op[i*64] = (bf16)lrelu_f((float)sp[i*64] + acc[i]);
}

// ================= segment-max pool =================
__global__ __launch_bounds__(256)
void pool_kernel(const bf16* __restrict__ h, int ldh, int cols,
                 const int* __restrict__ bs, const int* __restrict__ be,
                 float* __restrict__ g, int ldg, int gc0)
{
    int c = blockIdx.x*256 + threadIdx.x;
    int b = blockIdx.y;
    if (c >= cols) return;
    float m = -INFINITY;
    for (int n = bs[b]; n < be[b]; n++) m = fmaxf(m, (float)h[(size_t)n*ldh + c]);
    g[(size_t)b*ldg + gc0 + c] = (m == -INFINITY) ? 0.f : m;
}

// ================= row L2 normalize =================
__global__ __launch_bounds__(256)
void l2n_kernel(const float* __restrict__ in, float* __restrict__ outp,
                int cols, int ldi, int ldo)
{
    __shared__ float red[4];
    const int r = blockIdx.x;
    const int t = threadIdx.x;
    const float* ip = in + (size_t)r*ldi;
    float* op = outp + (size_t)r*ldo;
    float s = 0.f;
    for (int c=t; c<cols; c+=256){ float v = ip[c]; s += v*v; }
    #pragma unroll
    for (int o=32;o;o>>=1) s += __shfl_xor(s, o, 64);
    if ((t & 63) == 0) red[t>>6] = s;
    __syncthreads();
    float tot = red[0]+red[1]+red[2]+red[3];
    float inv = 1.0f / fmaxf(sqrtf(tot), 1e-12f);
    for (int c=t; c<cols; c+=256) op[c] = ip[c]*inv;
}

// ================= final 256->1 dot + sigmoid =================
__global__ __launch_bounds__(64)
void final_kernel(const float* __restrict__ f2, const float* __restrict__ w,
                  const float* __restrict__ b, float* __restrict__ outp)
{
    const int r = blockIdx.x;
    const int lane = threadIdx.x;
    const float* fp = f2 + (size_t)r*256;
    float s = 0.f;
    for (int c=lane; c<256; c+=64) s += fp[c]*w[c];
    #pragma unroll
    for (int o=32;o;o>>=1) s += __shfl_xor(s, o, 64);
    if (lane==0) outp[r] = 1.0f/(1.0f + expf(-(s + b[0])));
}

extern "C" void kernel_launch(void* const* d_in, const int* in_sizes, int n_in,
                              void* d_out, int out_size, void* d_ws, size_t ws_size,
                              hipStream_t stream)
{
    const float* x1  = (const float*)d_in[0];
    const int*   ei1 = (const int*)  d_in[1];
    const int*   bt1 = (const int*)  d_in[2];
    const float* x2  = (const float*)d_in[3];
    const int*   ei2 = (const int*)  d_in[4];
    const int*   bt2 = (const int*)  d_in[5];
    const float* cell= (const float*)d_in[6];
    const float* wq1=(const float*)d_in[7];  const float* bq1=(const float*)d_in[8];
    const float* wk1=(const float*)d_in[9];  const float* bk1=(const float*)d_in[10];
    const float* wv1=(const float*)d_in[11]; const float* bv1=(const float*)d_in[12];
    const float* ws1=(const float*)d_in[13]; const float* bs1=(const float*)d_in[14];
    const float* wq2=(const float*)d_in[15]; const float* bq2=(const float*)d_in[16];
    const float* wk2=(const float*)d_in[17]; const float* bk2=(const float*)d_in[18];
    const float* wv2=(const float*)d_in[19]; const float* bv2=(const float*)d_in[20];
    const float* ws2=(const float*)d_in[21]; const float* bs2=(const float*)d_in[22];
    const float* wg1=(const float*)d_in[23]; const float* bg1=(const float*)d_in[24];
    const float* wg2=(const float*)d_in[25]; const float* bg2=(const float*)d_in[26];
    const float* wr1=(const float*)d_in[27]; const float* br1=(const float*)d_in[28];
    const float* wr2=(const float*)d_in[29]; const float* br2=(const float*)d_in[30];
    const float* wr3=(const float*)d_in[31]; const float* br3=(const float*)d_in[32];
    const float* wf1=(const float*)d_in[33]; const float* bf1=(const float*)d_in[34];
    const float* gbn1=(const float*)d_in[35];const float* bbn1=(const float*)d_in[36];
    const float* wf2=(const float*)d_in[37]; const float* bf2=(const float*)d_in[38];
    const float* gbn2=(const float*)d_in[39];const float* bbn2=(const float*)d_in[40];
    const float* wf3=(const float*)d_in[41]; const float* bf3=(const float*)d_in[42];
    float* outp = (float*)d_out;
    (void)in_sizes; (void)n_in; (void)out_size; (void)ws_size;

    const float BNS = 1.0f / sqrtf(1.0f + 1e-5f);

    // ---- workspace arena (~101 MB peak) ----
    char* basep = (char*)d_ws;
    size_t off = 0;
    auto alloc = [&](size_t nbytes)->char* {
        char* p = basep + off;
        off += (nbytes + 255) & ~(size_t)255;
        return p;
    };
    float* xc   = (float*)alloc((size_t)BB*384*4);
    int* rowptr = (int*)  alloc((size_t)(NN+1)*4);
    int* cnt    = (int*)  alloc((size_t)NN*4);
    int* se     = (int*)  alloc((size_t)EE*4);
    int* bstart = (int*)  alloc((size_t)BB*4);
    int* bend   = (int*)  alloc((size_t)BB*4);
    float* g    = (float*)alloc((size_t)BB*1024*4);
    float* gh   = (float*)alloc((size_t)BB*512*4);
    float* cn   = (float*)alloc((size_t)BB*954*4);
    float* c1   = (float*)alloc((size_t)BB*512*4);
    float* c2   = (float*)alloc((size_t)BB*256*4);
    float* f1   = (float*)alloc((size_t)BB*512*4);
    float* f2   = (float*)alloc((size_t)BB*256*4);
    bf16* W1t   = (bf16*) alloc((size_t)1024*96*2);
    float* b1c  = (float*)alloc((size_t)1024*4);
    bf16* W2t   = (bf16*) alloc((size_t)2*2048*256*2);
    float* b2c  = (float*)alloc((size_t)4096*4);
    bf16* xa    = (bf16*) alloc((size_t)NN*96*2);
    bf16* h1    = (bf16*) alloc((size_t)NN*256*2);
    bf16* h2h   = (bf16*) alloc((size_t)NN*512*2);
    bf16* qkvs  = (bf16*) alloc((size_t)NN*2048*2);  // qkvs1 [NN,1024] then qkvs2h [NN,2048]

    // ---- one-time weight repack (per launch) ----
    prep_w1_kernel<<<(1024*96)/256,256,0,stream>>>(wq1,wk1,wv1,ws1, W1t);
    prep_b1_kernel<<<4,256,0,stream>>>(bq1,bk1,bv1,bs1, b1c);
    prep_w2_kernel<<<(2*2048*256)/256,256,0,stream>>>(wq2,wk2,wv2,ws2, W2t);
    prep_b2_kernel<<<16,256,0,stream>>>(bq2,bk2,bv2,bs2, b2c);

    for (int br=0; br<2; br++){
        const float* x  = br ? x2  : x1;
        const int*   ei = br ? ei2 : ei1;
        const int*   bt = br ? bt2 : bt1;
        float* gout = xc + br*128;

        // CSR of incoming edges + per-graph node ranges
        hipMemsetAsync(cnt, 0, (size_t)NN*4, stream);
        hist_kernel<<<EE/256,256,0,stream>>>(ei, cnt);
        scan_kernel<<<1,1024,0,stream>>>(cnt, rowptr);
        hipMemsetAsync(cnt, 0, (size_t)NN*4, stream);
        scatter_kernel<<<EE/256,256,0,stream>>>(ei, rowptr, cnt, se);
        hipMemsetAsync(bstart, 0, (size_t)BB*4, stream);
        hipMemsetAsync(bend,   0, (size_t)BB*4, stream);
        range_kernel<<<NN/256,256,0,stream>>>(bt, bstart, bend);

        // ---- layer 1: fused q|k|v|s GEMM [NN,96]x[96,1024] ----
        cvt_x_kernel<<<(NN*96)/256,256,0,stream>>>(x, xa);
        mfma_gemm<<<dim3(1024/128, NN/128),256,0,stream>>>(xa,96, W1t,96, b1c, qkvs,1024, 96);
        attn_kernel<128><<<NN*2/4,256,0,stream>>>(qkvs,1024, 0,256,512,768, 2, h1,256,0, rowptr,se,ei);

        // ---- layer 2: per head fused q|k|v|s GEMM [NN,256]x[256,2048] ----
        for (int h=0; h<2; h++){
            mfma_gemm<<<dim3(2048/128, NN/128),256,0,stream>>>(h1,256, W2t + (size_t)h*2048*256,256,
                                                               b2c + h*2048, qkvs,2048, 256);
            attn_kernel<512><<<NN/4,256,0,stream>>>(qkvs,2048, 0,512,1024,1536, 1, h2h,512,0, rowptr,se,ei);
            pool_kernel<<<dim3(2,BB),256,0,stream>>>(h2h,512,512,bstart,bend, g,1024, h*512);
        }

        // ---- graph head: 1024 -> 512 (lrelu) -> 128, then row-l2n ----
        gemm_kernel<1><<<dim3(8,8),256,0,stream>>>(g,1024, wg1,512, bg1, nullptr,nullptr,1.f, gh,512, BB,512,1024);
        gemm_kernel<0><<<dim3(2,8),256,0,stream>>>(gh,512, wg2,128, bg2, nullptr,nullptr,1.f, gout,384, BB,128,512);
        l2n_kernel<<<BB,256,0,stream>>>(gout, gout, 128, 384, 384);
    }

    // ---- cell branch ----
    l2n_kernel<<<BB,256,0,stream>>>(cell, cn, 954, 954, 954);
    gemm_kernel<1><<<dim3(8,8),256,0,stream>>>(cn,954, wr1,512, br1, nullptr,nullptr,1.f, c1,512, BB,512,954);
    gemm_kernel<1><<<dim3(4,8),256,0,stream>>>(c1,512, wr2,256, br2, nullptr,nullptr,1.f, c2,256, BB,256,512);
    gemm_kernel<0><<<dim3(2,8),256,0,stream>>>(c2,256, wr3,128, br3, nullptr,nullptr,1.f, xc+256,384, BB,128,256);

    // ---- head MLP ----
    l2n_kernel<<<BB,256,0,stream>>>(xc, xc, 384, 384, 384);
    gemm_kernel<2><<<dim3(8,8),256,0,stream>>>(xc,384, wf1,512, bf1, gbn1,bbn1,BNS, f1,512, BB,512,384);
    gemm_kernel<2><<<dim3(4,8),256,0,stream>>>(f1,512, wf2,256, bf2, gbn2,bbn2,BNS, f2,256, BB,256,512);
    final_kernel<<<BB,64,0,stream>>>(f2, wf3, bf3, outp);
}

// Round 3
// 946.776 us; speedup vs baseline: 2.8554x; 1.5609x over previous
//
#include <hip/hip_runtime.h>
#include <hip/hip_bf16.h>
#include <math.h>
#include <stdint.h>

typedef __hip_bfloat16 bf16;

#define NN 16384
#define EE 65536
#define BB 512

typedef __attribute__((ext_vector_type(8))) short short8;
typedef __attribute__((ext_vector_type(4))) float floatx4;

__device__ __forceinline__ float lrelu_f(float x){ return x >= 0.f ? x : 0.01f*x; }

// async 16B global->LDS. LDS dest is wave-uniform base; lane i lands at base+16*i.
__device__ __forceinline__ void gl2lds16(const void* g, void* l){
    __builtin_amdgcn_global_load_lds(
        (__attribute__((address_space(1))) unsigned int*)(uintptr_t)g,
        (__attribute__((address_space(3))) unsigned int*)(uintptr_t)l, 16, 0, 0);
}

// ================= MFMA bf16 GEMM: C[m,n] = A[m,:K] @ W[:,n] + bias[n] =================
// A: bf16 [M, lda] row-major. Bt: bf16 [N, ldb] N-MAJOR k-contiguous (Bt[n][k] = W[k][n]).
// C: bf16 [M, ldc]. M,N multiples of 128; K mult of 32.
__global__ __launch_bounds__(256)
void mfma_gemm(const bf16* __restrict__ A, int lda,
               const bf16* __restrict__ Bt, int ldb,
               const float* __restrict__ bias,
               bf16* __restrict__ C, int ldc, int K)
{
    __shared__ bf16 As[128*32];   // As[r][k]
    __shared__ bf16 Bs[128*32];   // Bs[n][k]
    const int tid  = threadIdx.x;
    const int wave = tid >> 6;
    const int lane = tid & 63;
    const int wm = (wave & 1) * 64;
    const int wn = (wave >> 1) * 64;
    const int m0 = blockIdx.y * 128;
    const int n0 = blockIdx.x * 128;

    const int srow = lane >> 2;
    const int scol = (lane & 3) * 8;
    const int arow = lane & 15;
    const int aq   = (lane >> 4) * 8;

    floatx4 acc[4][4];
    #pragma unroll
    for (int i=0;i<4;i++)
        #pragma unroll
        for (int j=0;j<4;j++) acc[i][j] = (floatx4){0.f,0.f,0.f,0.f};

    for (int k0 = 0; k0 < K; k0 += 32) {
        #pragma unroll
        for (int i = 0; i < 2; i++) {
            const int chunk = wave*2 + i;
            const int r = chunk*16 + srow;
            gl2lds16(A  + (size_t)(m0 + r)*lda + k0 + scol, As + chunk*512);
            gl2lds16(Bt + (size_t)(n0 + r)*ldb + k0 + scol, Bs + chunk*512);
        }
        __syncthreads();
        short8 af[4], bf_[4];
        #pragma unroll
        for (int i=0;i<4;i++) af[i]  = *(const short8*)(As + (wm + i*16 + arow)*32 + aq);
        #pragma unroll
        for (int j=0;j<4;j++) bf_[j] = *(const short8*)(Bs + (wn + j*16 + arow)*32 + aq);
        #pragma unroll
        for (int i=0;i<4;i++)
            #pragma unroll
            for (int j=0;j<4;j++)
                acc[i][j] = __builtin_amdgcn_mfma_f32_16x16x32_bf16(af[i], bf_[j], acc[i][j], 0,0,0);
        __syncthreads();
    }
    const int crow = (lane >> 4) * 4;
    const int ccol = lane & 15;
    #pragma unroll
    for (int j=0;j<4;j++){
        const int n = n0 + wn + j*16 + ccol;
        const float bs = bias[n];
        #pragma unroll
        for (int i=0;i<4;i++){
            const int m = m0 + wm + i*16 + crow;
            #pragma unroll
            for (int r=0;r<4;r++)
                C[(size_t)(m + r)*ldc + n] = (bf16)(acc[i][j][r] + bs);
        }
    }
}

// ================= weight/bias/activation prep =================
__global__ void cvt_x_kernel(const float* __restrict__ x, bf16* __restrict__ xa){
    int i = blockIdx.x*256 + threadIdx.x;
    int r = i / 96, c = i - r*96;
    xa[i] = (c < 78) ? (bf16)x[(size_t)r*78 + c] : (bf16)0.f;
}

__global__ void prep_w1_kernel(const float* __restrict__ wq, const float* __restrict__ wk,
                               const float* __restrict__ wv, const float* __restrict__ ws,
                               bf16* __restrict__ W1t){
    int i = blockIdx.x*256 + threadIdx.x;          // 1024*96
    int n = i / 96, k = i - n*96;
    const float* w = (n<256)?wq:(n<512)?wk:(n<768)?wv:ws;
    int col = n & 255;
    W1t[i] = (k < 78) ? (bf16)w[(size_t)k*256 + col] : (bf16)0.f;
}

__global__ void prep_b1_kernel(const float* __restrict__ bq, const float* __restrict__ bk,
                               const float* __restrict__ bv, const float* __restrict__ bs,
                               float* __restrict__ b1c){
    int i = blockIdx.x*256 + threadIdx.x;
    if (i >= 1024) return;
    const float* b = (i<256)?bq:(i<512)?bk:(i<768)?bv:bs;
    b1c[i] = b[i & 255];
}

__global__ void prep_w2_kernel(const float* __restrict__ wq, const float* __restrict__ wk,
                               const float* __restrict__ wv, const float* __restrict__ ws,
                               bf16* __restrict__ W2t){
    int i = blockIdx.x*256 + threadIdx.x;          // 2*2048*256
    int k = i & 255;
    int j = (i >> 8) & 2047;
    int h = i >> 19;
    const float* w = (j<512)?wq:(j<1024)?wk:(j<1536)?wv:ws;
    int col = h*512 + (j & 511);
    W2t[i] = (bf16)w[(size_t)k*1024 + col];
}

__global__ void prep_b2_kernel(const float* __restrict__ bq, const float* __restrict__ bk,
                               const float* __restrict__ bv, const float* __restrict__ bs,
                               float* __restrict__ b2c){
    int i = blockIdx.x*256 + threadIdx.x;
    if (i >= 4096) return;
    int j = i & 2047, h = i >> 11;
    const float* b = (j<512)?bq:(j<1024)?bk:(j<1536)?bv:bs;
    b2c[i] = b[h*512 + (j & 511)];
}

// ================= split-K fp32 GEMM for B=512 MLP heads =================
// P[s][m][n] = A[m, sKc:(s+1)Kc] @ W[sKc:(s+1)Kc, n]   (deterministic partials)
__global__ __launch_bounds__(256)
void skgemm_partial(const float* __restrict__ A, int lda,
                    const float* __restrict__ W, int ldw,
                    float* __restrict__ P,
                    int M, int N, int K, int Kc)
{
    __shared__ float As[16][68];
    __shared__ float Bs[16][68];
    const int tid = threadIdx.x;
    const int tx = tid & 15;
    const int ty = tid >> 4;
    const int m0 = blockIdx.y * 64;
    const int n0 = blockIdx.x * 64;
    const int s  = blockIdx.z;
    const int kb = s * Kc;
    const int ke = min(K, kb + Kc);
    float acc[4][4];
    #pragma unroll
    for (int i=0;i<4;i++)
        #pragma unroll
        for (int j=0;j<4;j++) acc[i][j]=0.f;

    for (int k0=kb; k0<ke; k0+=16) {
        #pragma unroll
        for (int i=0;i<4;i++){
            int idx = tid + i*256;
            int r = idx >> 4, c = idx & 15;
            int kk = k0 + c;
            As[c][r] = (kk < ke) ? A[(size_t)(m0+r)*lda + kk] : 0.f;
        }
        #pragma unroll
        for (int i=0;i<4;i++){
            int idx = tid + i*256;
            int r = idx >> 6, c = idx & 63;
            int kk = k0 + r;
            Bs[r][c] = (kk < ke) ? W[(size_t)kk*ldw + n0 + c] : 0.f;
        }
        __syncthreads();
        #pragma unroll
        for (int kk=0;kk<16;kk++){
            float a[4], b[4];
            #pragma unroll
            for (int i=0;i<4;i++) a[i] = As[kk][ty*4+i];
            #pragma unroll
            for (int j=0;j<4;j++) b[j] = Bs[kk][tx*4+j];
            #pragma unroll
            for (int i=0;i<4;i++)
                #pragma unroll
                for (int j=0;j<4;j++) acc[i][j] += a[i]*b[j];
        }
        __syncthreads();
    }
    float* Pp = P + (size_t)s*M*N;
    #pragma unroll
    for (int i=0;i<4;i++){
        int m = m0 + ty*4 + i;
        #pragma unroll
        for (int j=0;j<4;j++){
            int n = n0 + tx*4 + j;
            Pp[(size_t)m*N + n] = acc[i][j];
        }
    }
}

// reduce S partials + bias + activation. ACT: 0 none, 1 lrelu, 2 BN+lrelu
template<int ACT>
__global__ __launch_bounds__(256)
void skgemm_reduce(const float* __restrict__ P,
                   const float* __restrict__ bias,
                   const float* __restrict__ gamma,
                   const float* __restrict__ beta,
                   float bnscale,
                   float* __restrict__ C, int ldc,
                   int M, int N, int S)
{
    int i = blockIdx.x*256 + threadIdx.x;
    if (i >= M*N) return;
    int m = i / N, n = i - m*N;
    float v = 0.f;
    for (int s=0; s<S; s++) v += P[(size_t)s*M*N + i];
    v += bias[n];
    if (ACT==1) v = lrelu_f(v);
    if (ACT==2) { v = v*bnscale*gamma[n] + beta[n]; v = lrelu_f(v); }
    C[(size_t)m*ldc + n] = v;
}

// ================= CSR build =================
__global__ void hist_kernel(const int* __restrict__ ei, int* __restrict__ cnt){
    int e = blockIdx.x*256 + threadIdx.x;
    atomicAdd(&cnt[ei[EE + e]], 1);
}

__global__ __launch_bounds__(1024)
void scan_kernel(const int* __restrict__ hist, int* __restrict__ rowptr){
    __shared__ int sums[1024];
    const int t = threadIdx.x;
    const int base = t*16;
    int loc[16]; int s = 0;
    #pragma unroll
    for (int i=0;i<16;i++){ loc[i]=s; s += hist[base+i]; }
    sums[t] = s; __syncthreads();
    for (int o=1;o<1024;o<<=1){
        int v = (t>=o) ? sums[t-o] : 0;
        __syncthreads();
        sums[t] += v;
        __syncthreads();
    }
    int pref = (t>0) ? sums[t-1] : 0;
    #pragma unroll
    for (int i=0;i<16;i++) rowptr[base+i] = pref + loc[i];
    if (t==1023) rowptr[NN] = sums[1023];
}

__global__ void scatter_kernel(const int* __restrict__ ei, const int* __restrict__ rowptr,
                               int* __restrict__ cnt, int* __restrict__ se){
    int e = blockIdx.x*256 + threadIdx.x;
    int d = ei[EE + e];
    int pos = rowptr[d] + atomicAdd(&cnt[d], 1);
    se[pos] = e;
}

__global__ void range_kernel(const int* __restrict__ bt, int* __restrict__ bs, int* __restrict__ be){
    int n = blockIdx.x*256 + threadIdx.x;
    int b = bt[n];
    if (n==0     || bt[n-1]!=b) bs[b] = n;
    if (n==NN-1  || bt[n+1]!=b) be[b] = n+1;
}

// ================= attention: one wave per (dst node, head) =================
template<int D>
__global__ __launch_bounds__(256)
void attn_kernel(const bf16* __restrict__ qkvs, int ld, int qo, int ko, int vo, int so, int H,
                 bf16* __restrict__ hout, int ldo, int oo,
                 const int* __restrict__ rowptr, const int* __restrict__ se,
                 const int* __restrict__ ei)
{
    constexpr int PER = D / 64;
    const int lane = threadIdx.x & 63;
    const int gw = blockIdx.x * 4 + (threadIdx.x >> 6);
    const int n = gw / H;
    const int h = gw - n*H;
    const float scale = rsqrtf((float)D);
    const int hd = h*D + lane;

    const bf16* qp = qkvs + (size_t)n*ld + qo + hd;
    float qr[PER];
    #pragma unroll
    for (int i=0;i<PER;i++) qr[i] = (float)qp[i*64];

    const int e0 = rowptr[n], e1 = rowptr[n+1];
    float m = -INFINITY, z = 0.f;
    for (int p=e0; p<e1; p++){
        const int src = ei[se[p]];
        const bf16* kp = qkvs + (size_t)src*ld + ko + hd;
        float dot = 0.f;
        #pragma unroll
        for (int i=0;i<PER;i++) dot += qr[i] * (float)kp[i*64];
        #pragma unroll
        for (int o=32;o;o>>=1) dot += __shfl_xor(dot, o, 64);
        dot *= scale;
        if (dot > m){ z *= expf(m - dot); m = dot; }
        z += expf(dot - m);
    }
    const float invz = 1.0f / (z + 1e-16f);

    float acc[PER];
    #pragma unroll
    for (int i=0;i<PER;i++) acc[i] = 0.f;
    for (int p=e0; p<e1; p++){
        const int src = ei[se[p]];
        const bf16* kp = qkvs + (size_t)src*ld + ko + hd;
        float dot = 0.f;
        #pragma unroll
        for (int i=0;i<PER;i++) dot += qr[i] * (float)kp[i*64];
        #pragma unroll
        for (int o=32;o;o>>=1) dot += __shfl_xor(dot, o, 64);
        dot *= scale;
        const float alpha = expf(dot - m) * invz;
        const bf16* vp = qkvs + (size_t)src*ld + vo + hd;
        #pragma unroll
        for (int i=0;i<PER;i++) acc[i] += alpha * (float)vp[i*64];
    }
    const bf16* sp = qkvs + (size_t)n*ld + so + hd;
    bf16* op = hout + (size_t)n*ldo + oo + hd;
    #pragma unroll
    for (int i=0;i<PER;i++) op[i*64] = (bf16)lrelu_f((float)sp[i*64] + acc[i]);
}

// ================= segment-max pool =================
__global__ __launch_bounds__(256)
void pool_kernel(const bf16* __restrict__ h, int ldh, int cols,
                 const int* __restrict__ bs, const int* __restrict__ be,
                 float* __restrict__ g, int ldg, int gc0)
{
    int c = blockIdx.x*256 + threadIdx.x;
    int b = blockIdx.y;
    if (c >= cols) return;
    float m = -INFINITY;
    for (int n = bs[b]; n < be[b]; n++) m = fmaxf(m, (float)h[(size_t)n*ldh + c]);
    g[(size_t)b*ldg + gc0 + c] = (m == -INFINITY) ? 0.f : m;
}

// ================= row L2 normalize =================
__global__ __launch_bounds__(256)
void l2n_kernel(const float* __restrict__ in, float* __restrict__ outp,
                int cols, int ldi, int ldo)
{
    __shared__ float red[4];
    const int r = blockIdx.x;
    const int t = threadIdx.x;
    const float* ip = in + (size_t)r*ldi;
    float* op = outp + (size_t)r*ldo;
    float s = 0.f;
    for (int c=t; c<cols; c+=256){ float v = ip[c]; s += v*v; }
    #pragma unroll
    for (int o=32;o;o>>=1) s += __shfl_xor(s, o, 64);
    if ((t & 63) == 0) red[t>>6] = s;
    __syncthreads();
    float tot = red[0]+red[1]+red[2]+red[3];
    float inv = 1.0f / fmaxf(sqrtf(tot), 1e-12f);
    for (int c=t; c<cols; c+=256) op[c] = ip[c]*inv;
}

// ================= final 256->1 dot + sigmoid =================
__global__ __launch_bounds__(64)
void final_kernel(const float* __restrict__ f2, const float* __restrict__ w,
                  const float* __restrict__ b, float* __restrict__ outp)
{
    const int r = blockIdx.x;
    const int lane = threadIdx.x;
    const float* fp = f2 + (size_t)r*256;
    float s = 0.f;
    for (int c=lane; c<256; c+=64) s += fp[c]*w[c];
    #pragma unroll
    for (int o=32;o;o>>=1) s += __shfl_xor(s, o, 64);
    if (lane==0) outp[r] = 1.0f/(1.0f + expf(-(s + b[0])));
}

extern "C" void kernel_launch(void* const* d_in, const int* in_sizes, int n_in,
                              void* d_out, int out_size, void* d_ws, size_t ws_size,
                              hipStream_t stream)
{
    const float* x1  = (const float*)d_in[0];
    const int*   ei1 = (const int*)  d_in[1];
    const int*   bt1 = (const int*)  d_in[2];
    const float* x2  = (const float*)d_in[3];
    const int*   ei2 = (const int*)  d_in[4];
    const int*   bt2 = (const int*)  d_in[5];
    const float* cell= (const float*)d_in[6];
    const float* wq1=(const float*)d_in[7];  const float* bq1=(const float*)d_in[8];
    const float* wk1=(const float*)d_in[9];  const float* bk1=(const float*)d_in[10];
    const float* wv1=(const float*)d_in[11]; const float* bv1=(const float*)d_in[12];
    const float* ws1=(const float*)d_in[13]; const float* bs1=(const float*)d_in[14];
    const float* wq2=(const float*)d_in[15]; const float* bq2=(const float*)d_in[16];
    const float* wk2=(const float*)d_in[17]; const float* bk2=(const float*)d_in[18];
    const float* wv2=(const float*)d_in[19]; const float* bv2=(const float*)d_in[20];
    const float* ws2=(const float*)d_in[21]; const float* bs2=(const float*)d_in[22];
    const float* wg1=(const float*)d_in[23]; const float* bg1=(const float*)d_in[24];
    const float* wg2=(const float*)d_in[25]; const float* bg2=(const float*)d_in[26];
    const float* wr1=(const float*)d_in[27]; const float* br1=(const float*)d_in[28];
    const float* wr2=(const float*)d_in[29]; const float* br2=(const float*)d_in[30];
    const float* wr3=(const float*)d_in[31]; const float* br3=(const float*)d_in[32];
    const float* wf1=(const float*)d_in[33]; const float* bf1=(const float*)d_in[34];
    const float* gbn1=(const float*)d_in[35];const float* bbn1=(const float*)d_in[36];
    const float* wf2=(const float*)d_in[37]; const float* bf2=(const float*)d_in[38];
    const float* gbn2=(const float*)d_in[39];const float* bbn2=(const float*)d_in[40];
    const float* wf3=(const float*)d_in[41]; const float* bf3=(const float*)d_in[42];
    float* outp = (float*)d_out;
    (void)in_sizes; (void)n_in; (void)out_size; (void)ws_size;

    const float BNS = 1.0f / sqrtf(1.0f + 1e-5f);

    // ---- workspace arena (~103 MB peak; pbuf aliases dead qkvs) ----
    char* basep = (char*)d_ws;
    size_t off = 0;
    auto alloc = [&](size_t nbytes)->char* {
        char* p = basep + off;
        off += (nbytes + 255) & ~(size_t)255;
        return p;
    };
    float* xc   = (float*)alloc((size_t)BB*384*4);
    int* rowptr = (int*)  alloc((size_t)(NN+1)*4);
    int* cnt    = (int*)  alloc((size_t)NN*4);
    int* se     = (int*)  alloc((size_t)EE*4);
    int* bstart = (int*)  alloc((size_t)BB*4);
    int* bend   = (int*)  alloc((size_t)BB*4);
    float* g    = (float*)alloc((size_t)BB*1024*4);
    float* gh   = (float*)alloc((size_t)BB*512*4);
    float* cn   = (float*)alloc((size_t)BB*954*4);
    float* c1   = (float*)alloc((size_t)BB*512*4);
    float* c2   = (float*)alloc((size_t)BB*256*4);
    float* f1   = (float*)alloc((size_t)BB*512*4);
    float* f2   = (float*)alloc((size_t)BB*256*4);
    bf16* W1t   = (bf16*) alloc((size_t)1024*96*2);
    float* b1c  = (float*)alloc((size_t)1024*4);
    bf16* W2t   = (bf16*) alloc((size_t)2*2048*256*2);
    float* b2c  = (float*)alloc((size_t)4096*4);
    bf16* xa    = (bf16*) alloc((size_t)NN*96*2);
    bf16* h1    = (bf16*) alloc((size_t)NN*256*2);
    bf16* h2h   = (bf16*) alloc((size_t)NN*512*2);
    bf16* qkvs  = (bf16*) alloc((size_t)NN*2048*2);
    // split-K partial buffer: used only when qkvs content is dead (head MLPs)
    float* pbuf = (float*)qkvs;   // needs 8*512*512*4 = 8 MB << 64 MB

    // ---- one-time weight repack (per launch) ----
    prep_w1_kernel<<<(1024*96)/256,256,0,stream>>>(wq1,wk1,wv1,ws1, W1t);
    prep_b1_kernel<<<4,256,0,stream>>>(bq1,bk1,bv1,bs1, b1c);
    prep_w2_kernel<<<(2*2048*256)/256,256,0,stream>>>(wq2,wk2,wv2,ws2, W2t);
    prep_b2_kernel<<<16,256,0,stream>>>(bq2,bk2,bv2,bs2, b2c);

    for (int br=0; br<2; br++){
        const float* x  = br ? x2  : x1;
        const int*   ei = br ? ei2 : ei1;
        const int*   bt = br ? bt2 : bt1;
        float* gout = xc + br*128;

        // CSR of incoming edges + per-graph node ranges
        hipMemsetAsync(cnt, 0, (size_t)NN*4, stream);
        hist_kernel<<<EE/256,256,0,stream>>>(ei, cnt);
        scan_kernel<<<1,1024,0,stream>>>(cnt, rowptr);
        hipMemsetAsync(cnt, 0, (size_t)NN*4, stream);
        scatter_kernel<<<EE/256,256,0,stream>>>(ei, rowptr, cnt, se);
        hipMemsetAsync(bstart, 0, (size_t)BB*4, stream);
        hipMemsetAsync(bend,   0, (size_t)BB*4, stream);
        range_kernel<<<NN/256,256,0,stream>>>(bt, bstart, bend);

        // ---- layer 1: fused q|k|v|s GEMM [NN,96]x[96,1024] ----
        cvt_x_kernel<<<(NN*96)/256,256,0,stream>>>(x, xa);
        mfma_gemm<<<dim3(1024/128, NN/128),256,0,stream>>>(xa,96, W1t,96, b1c, qkvs,1024, 96);
        attn_kernel<128><<<NN*2/4,256,0,stream>>>(qkvs,1024, 0,256,512,768, 2, h1,256,0, rowptr,se,ei);

        // ---- layer 2: per head fused q|k|v|s GEMM [NN,256]x[256,2048] ----
        for (int h=0; h<2; h++){
            mfma_gemm<<<dim3(2048/128, NN/128),256,0,stream>>>(h1,256, W2t + (size_t)h*2048*256,256,
                                                               b2c + h*2048, qkvs,2048, 256);
            attn_kernel<512><<<NN/4,256,0,stream>>>(qkvs,2048, 0,512,1024,1536, 1, h2h,512,0, rowptr,se,ei);
            pool_kernel<<<dim3(2,BB),256,0,stream>>>(h2h,512,512,bstart,bend, g,1024, h*512);
        }

        // ---- graph head (split-K fp32): 1024 -> 512 lrelu -> 128, then l2n ----
        skgemm_partial<<<dim3(8,8,8),256,0,stream>>>(g,1024, wg1,512, pbuf, BB,512,1024,128);
        skgemm_reduce<1><<<(BB*512)/256,256,0,stream>>>(pbuf, bg1, nullptr,nullptr,1.f, gh,512, BB,512,8);
        skgemm_partial<<<dim3(2,8,8),256,0,stream>>>(gh,512, wg2,128, pbuf, BB,128,512,64);
        skgemm_reduce<0><<<(BB*128)/256,256,0,stream>>>(pbuf, bg2, nullptr,nullptr,1.f, gout,384, BB,128,8);
        l2n_kernel<<<BB,256,0,stream>>>(gout, gout, 128, 384, 384);
    }

    // ---- cell branch (split-K fp32) ----
    l2n_kernel<<<BB,256,0,stream>>>(cell, cn, 954, 954, 954);
    skgemm_partial<<<dim3(8,8,8),256,0,stream>>>(cn,954, wr1,512, pbuf, BB,512,954,120);
    skgemm_reduce<1><<<(BB*512)/256,256,0,stream>>>(pbuf, br1, nullptr,nullptr,1.f, c1,512, BB,512,8);
    skgemm_partial<<<dim3(4,8,8),256,0,stream>>>(c1,512, wr2,256, pbuf, BB,256,512,64);
    skgemm_reduce<1><<<(BB*256)/256,256,0,stream>>>(pbuf, br2, nullptr,nullptr,1.f, c2,256, BB,256,8);
    skgemm_partial<<<dim3(2,8,8),256,0,stream>>>(c2,256, wr3,128, pbuf, BB,128,256,32);
    skgemm_reduce<0><<<(BB*128)/256,256,0,stream>>>(pbuf, br3, nullptr,nullptr,1.f, xc+256,384, BB,128,8);

    // ---- head MLP (split-K fp32 + fused BN) ----
    l2n_kernel<<<BB,256,0,stream>>>(xc, xc, 384, 384, 384);
    skgemm_partial<<<dim3(8,8,8),256,0,stream>>>(xc,384, wf1,512, pbuf, BB,512,384,48);
    skgemm_reduce<2><<<(BB*512)/256,256,0,stream>>>(pbuf, bf1, gbn1,bbn1,BNS, f1,512, BB,512,8);
    skgemm_partial<<<dim3(4,8,8),256,0,stream>>>(f1,512, wf2,256, pbuf, BB,256,512,64);
    skgemm_reduce<2><<<(BB*256)/256,256,0,stream>>>(pbuf, bf2, gbn2,bbn2,BNS, f2,256, BB,256,8);
    final_kernel<<<BB,64,0,stream>>>(f2, wf3, bf3, outp);
}

// Round 4
// 801.311 us; speedup vs baseline: 3.3738x; 1.1815x over previous
//
#include <hip/hip_runtime.h>
#include <hip/hip_bf16.h>
#include <math.h>
#include <stdint.h>

typedef __hip_bfloat16 bf16;

#define NN 16384
#define EE 65536
#define BB 512

typedef __attribute__((ext_vector_type(8))) short short8;
typedef __attribute__((ext_vector_type(4))) float floatx4;

__device__ __forceinline__ float lrelu_f(float x){ return x >= 0.f ? x : 0.01f*x; }

__device__ __forceinline__ float b2f(short s){
    unsigned int u = ((unsigned int)(unsigned short)s) << 16;
    float f; __builtin_memcpy(&f, &u, 4); return f;
}
__device__ __forceinline__ short f2b(float f){
    bf16 b = (bf16)f;
    short s; __builtin_memcpy(&s, &b, 2); return s;
}

// async 16B global->LDS. LDS dest is wave-uniform base; lane i lands at base+16*i.
__device__ __forceinline__ void gl2lds16(const void* g, void* l){
    __builtin_amdgcn_global_load_lds(
        (__attribute__((address_space(1))) unsigned int*)(uintptr_t)g,
        (__attribute__((address_space(3))) unsigned int*)(uintptr_t)l, 16, 0, 0);
}

// ================= MFMA bf16 GEMM: C[m,n] = A[m,:K] @ W[:,n] + bias[n] =================
// A: bf16 [M, lda] row-major. Bt: bf16 [N, ldb] N-MAJOR k-contiguous (Bt[n][k] = W[k][n]).
// C: bf16 [M, ldc]. M,N multiples of 128; K mult of 32.
__global__ __launch_bounds__(256)
void mfma_gemm(const bf16* __restrict__ A, int lda,
               const bf16* __restrict__ Bt, int ldb,
               const float* __restrict__ bias,
               bf16* __restrict__ C, int ldc, int K)
{
    __shared__ bf16 As[128*32];   // As[r][k]
    __shared__ bf16 Bs[128*32];   // Bs[n][k]
    const int tid  = threadIdx.x;
    const int wave = tid >> 6;
    const int lane = tid & 63;
    const int wm = (wave & 1) * 64;
    const int wn = (wave >> 1) * 64;
    const int m0 = blockIdx.y * 128;
    const int n0 = blockIdx.x * 128;

    const int srow = lane >> 2;
    const int scol = (lane & 3) * 8;
    const int arow = lane & 15;
    const int aq   = (lane >> 4) * 8;

    floatx4 acc[4][4];
    #pragma unroll
    for (int i=0;i<4;i++)
        #pragma unroll
        for (int j=0;j<4;j++) acc[i][j] = (floatx4){0.f,0.f,0.f,0.f};

    for (int k0 = 0; k0 < K; k0 += 32) {
        #pragma unroll
        for (int i = 0; i < 2; i++) {
            const int chunk = wave*2 + i;
            const int r = chunk*16 + srow;
            gl2lds16(A  + (size_t)(m0 + r)*lda + k0 + scol, As + chunk*512);
            gl2lds16(Bt + (size_t)(n0 + r)*ldb + k0 + scol, Bs + chunk*512);
        }
        __syncthreads();
        short8 af[4], bf_[4];
        #pragma unroll
        for (int i=0;i<4;i++) af[i]  = *(const short8*)(As + (wm + i*16 + arow)*32 + aq);
        #pragma unroll
        for (int j=0;j<4;j++) bf_[j] = *(const short8*)(Bs + (wn + j*16 + arow)*32 + aq);
        #pragma unroll
        for (int i=0;i<4;i++)
            #pragma unroll
            for (int j=0;j<4;j++)
                acc[i][j] = __builtin_amdgcn_mfma_f32_16x16x32_bf16(af[i], bf_[j], acc[i][j], 0,0,0);
        __syncthreads();
    }
    const int crow = (lane >> 4) * 4;
    const int ccol = lane & 15;
    #pragma unroll
    for (int j=0;j<4;j++){
        const int n = n0 + wn + j*16 + ccol;
        const float bs = bias[n];
        #pragma unroll
        for (int i=0;i<4;i++){
            const int m = m0 + wm + i*16 + crow;
            #pragma unroll
            for (int r=0;r<4;r++)
                C[(size_t)(m + r)*ldc + n] = (bf16)(acc[i][j][r] + bs);
        }
    }
}

// ================= weight/bias/activation prep =================
__global__ void cvt_x_kernel(const float* __restrict__ x, bf16* __restrict__ xa){
    int i = blockIdx.x*256 + threadIdx.x;
    int r = i / 96, c = i - r*96;
    xa[i] = (c < 78) ? (bf16)x[(size_t)r*78 + c] : (bf16)0.f;
}

__global__ void prep_w1_kernel(const float* __restrict__ wq, const float* __restrict__ wk,
                               const float* __restrict__ wv, const float* __restrict__ ws,
                               bf16* __restrict__ W1t){
    int i = blockIdx.x*256 + threadIdx.x;          // 1024*96
    int n = i / 96, k = i - n*96;
    const float* w = (n<256)?wq:(n<512)?wk:(n<768)?wv:ws;
    int col = n & 255;
    W1t[i] = (k < 78) ? (bf16)w[(size_t)k*256 + col] : (bf16)0.f;
}

__global__ void prep_b1_kernel(const float* __restrict__ bq, const float* __restrict__ bk,
                               const float* __restrict__ bv, const float* __restrict__ bs,
                               float* __restrict__ b1c){
    int i = blockIdx.x*256 + threadIdx.x;
    if (i >= 1024) return;
    const float* b = (i<256)?bq:(i<512)?bk:(i<768)?bv:bs;
    b1c[i] = b[i & 255];
}

__global__ void prep_w2_kernel(const float* __restrict__ wq, const float* __restrict__ wk,
                               const float* __restrict__ wv, const float* __restrict__ ws,
                               bf16* __restrict__ W2t){
    int i = blockIdx.x*256 + threadIdx.x;          // 2*2048*256
    int k = i & 255;
    int j = (i >> 8) & 2047;
    int h = i >> 19;
    const float* w = (j<512)?wq:(j<1024)?wk:(j<1536)?wv:ws;
    int col = h*512 + (j & 511);
    W2t[i] = (bf16)w[(size_t)k*1024 + col];
}

__global__ void prep_b2_kernel(const float* __restrict__ bq, const float* __restrict__ bk,
                               const float* __restrict__ bv, const float* __restrict__ bs,
                               float* __restrict__ b2c){
    int i = blockIdx.x*256 + threadIdx.x;
    if (i >= 4096) return;
    int j = i & 2047, h = i >> 11;
    const float* b = (j<512)?bq:(j<1024)?bk:(j<1536)?bv:bs;
    b2c[i] = b[h*512 + (j & 511)];
}

// ================= split-K fp32 GEMM for B=512 MLP heads =================
__global__ __launch_bounds__(256)
void skgemm_partial(const float* __restrict__ A, int lda,
                    const float* __restrict__ W, int ldw,
                    float* __restrict__ P,
                    int M, int N, int K, int Kc)
{
    __shared__ float As[16][68];
    __shared__ float Bs[16][68];
    const int tid = threadIdx.x;
    const int tx = tid & 15;
    const int ty = tid >> 4;
    const int m0 = blockIdx.y * 64;
    const int n0 = blockIdx.x * 64;
    const int s  = blockIdx.z;
    const int kb = s * Kc;
    const int ke = min(K, kb + Kc);
    float acc[4][4];
    #pragma unroll
    for (int i=0;i<4;i++)
        #pragma unroll
        for (int j=0;j<4;j++) acc[i][j]=0.f;

    for (int k0=kb; k0<ke; k0+=16) {
        #pragma unroll
        for (int i=0;i<4;i++){
            int idx = tid + i*256;
            int r = idx >> 4, c = idx & 15;
            int kk = k0 + c;
            As[c][r] = (kk < ke) ? A[(size_t)(m0+r)*lda + kk] : 0.f;
        }
        #pragma unroll
        for (int i=0;i<4;i++){
            int idx = tid + i*256;
            int r = idx >> 6, c = idx & 63;
            int kk = k0 + r;
            Bs[r][c] = (kk < ke) ? W[(size_t)kk*ldw + n0 + c] : 0.f;
        }
        __syncthreads();
        #pragma unroll
        for (int kk=0;kk<16;kk++){
            float a[4], b[4];
            #pragma unroll
            for (int i=0;i<4;i++) a[i] = As[kk][ty*4+i];
            #pragma unroll
            for (int j=0;j<4;j++) b[j] = Bs[kk][tx*4+j];
            #pragma unroll
            for (int i=0;i<4;i++)
                #pragma unroll
                for (int j=0;j<4;j++) acc[i][j] += a[i]*b[j];
        }
        __syncthreads();
    }
    float* Pp = P + (size_t)s*M*N;
    #pragma unroll
    for (int i=0;i<4;i++){
        int m = m0 + ty*4 + i;
        #pragma unroll
        for (int j=0;j<4;j++){
            int n = n0 + tx*4 + j;
            Pp[(size_t)m*N + n] = acc[i][j];
        }
    }
}

template<int ACT>
__global__ __launch_bounds__(256)
void skgemm_reduce(const float* __restrict__ P,
                   const float* __restrict__ bias,
                   const float* __restrict__ gamma,
                   const float* __restrict__ beta,
                   float bnscale,
                   float* __restrict__ C, int ldc,
                   int M, int N, int S)
{
    int i = blockIdx.x*256 + threadIdx.x;
    if (i >= M*N) return;
    int m = i / N, n = i - m*N;
    float v = 0.f;
    for (int s=0; s<S; s++) v += P[(size_t)s*M*N + i];
    v += bias[n];
    if (ACT==1) v = lrelu_f(v);
    if (ACT==2) { v = v*bnscale*gamma[n] + beta[n]; v = lrelu_f(v); }
    C[(size_t)m*ldc + n] = v;
}

// ================= CSR build =================
__global__ void hist_kernel(const int* __restrict__ ei, int* __restrict__ cnt){
    int e = blockIdx.x*256 + threadIdx.x;
    atomicAdd(&cnt[ei[EE + e]], 1);
}

__global__ __launch_bounds__(1024)
void scan_kernel(const int* __restrict__ hist, int* __restrict__ rowptr){
    __shared__ int sums[1024];
    const int t = threadIdx.x;
    const int base = t*16;
    int loc[16]; int s = 0;
    #pragma unroll
    for (int i=0;i<16;i++){ loc[i]=s; s += hist[base+i]; }
    sums[t] = s; __syncthreads();
    for (int o=1;o<1024;o<<=1){
        int v = (t>=o) ? sums[t-o] : 0;
        __syncthreads();
        sums[t] += v;
        __syncthreads();
    }
    int pref = (t>0) ? sums[t-1] : 0;
    #pragma unroll
    for (int i=0;i<16;i++) rowptr[base+i] = pref + loc[i];
    if (t==1023) rowptr[NN] = sums[1023];
}

// stores SOURCE NODE ID directly (not edge id) -> one less indirection in attn
__global__ void scatter_kernel(const int* __restrict__ ei, const int* __restrict__ rowptr,
                               int* __restrict__ cnt, int* __restrict__ srcs){
    int e = blockIdx.x*256 + threadIdx.x;
    int d = ei[EE + e];
    int pos = rowptr[d] + atomicAdd(&cnt[d], 1);
    srcs[pos] = ei[e];
}

__global__ void range_kernel(const int* __restrict__ bt, int* __restrict__ bs, int* __restrict__ be){
    int n = blockIdx.x*256 + threadIdx.x;
    int b = bt[n];
    if (n==0     || bt[n-1]!=b) bs[b] = n;
    if (n==NN-1  || bt[n+1]!=b) be[b] = n+1;
}

// ================= attention: one wave per (dst node, head), single-pass online softmax ===
// lane owns contiguous PER=D/64 elements -> 16B (D=512) / 4B (D=128) vector loads.
template<int D>
__global__ __launch_bounds__(256)
void attn_kernel(const bf16* __restrict__ qkvs, int ld, int qo, int ko, int vo, int so, int H,
                 bf16* __restrict__ hout, int ldo, int oo,
                 const int* __restrict__ rowptr, const int* __restrict__ srcs)
{
    constexpr int PER = D / 64;
    typedef __attribute__((ext_vector_type(PER))) short shortP;
    const int lane = threadIdx.x & 63;
    const int gw = blockIdx.x * 4 + (threadIdx.x >> 6);
    const int n = gw / H;
    const int h = gw - n*H;
    const float scale = rsqrtf((float)D);
    const int hd = h*D + lane*PER;

    const shortP qv = *(const shortP*)(qkvs + (size_t)n*ld + qo + hd);
    float qr[PER];
    #pragma unroll
    for (int i=0;i<PER;i++) qr[i] = b2f(qv[i]);

    const int e0 = rowptr[n], e1 = rowptr[n+1];
    float m = -INFINITY, z = 0.f;
    float acc[PER];
    #pragma unroll
    for (int i=0;i<PER;i++) acc[i] = 0.f;

    for (int p=e0; p<e1; p++){
        const int src = srcs[p];
        const bf16* rp = qkvs + (size_t)src*ld;
        const shortP kv = *(const shortP*)(rp + ko + hd);
        const shortP vv = *(const shortP*)(rp + vo + hd);
        float dot = 0.f;
        #pragma unroll
        for (int i=0;i<PER;i++) dot += qr[i]*b2f(kv[i]);
        #pragma unroll
        for (int o=32;o;o>>=1) dot += __shfl_xor(dot, o, 64);
        dot *= scale;
        const float mn = fmaxf(m, dot);
        const float cs = expf(m - mn);    // ==0 on first edge (m=-inf), ==1 if max unchanged
        const float w  = expf(dot - mn);
        z = z*cs + w;
        #pragma unroll
        for (int i=0;i<PER;i++) acc[i] = acc[i]*cs + w*b2f(vv[i]);
        m = mn;
    }
    const float invz = 1.0f/(z + 1e-16f);
    const shortP sv = *(const shortP*)(qkvs + (size_t)n*ld + so + hd);
    shortP ov;
    #pragma unroll
    for (int i=0;i<PER;i++) ov[i] = f2b(lrelu_f(b2f(sv[i]) + acc[i]*invz));
    *(shortP*)(hout + (size_t)n*ldo + oo + hd) = ov;
}

// ================= segment-max pool (512 cols fixed, one block per graph) =================
__global__ __launch_bounds__(256)
void pool_kernel(const bf16* __restrict__ h, int ldh,
                 const int* __restrict__ bs, const int* __restrict__ be,
                 float* __restrict__ g, int ldg, int gc0)
{
    typedef __attribute__((ext_vector_type(2))) short short2v;
    const int c = threadIdx.x * 2;          // 512 cols
    const int b = blockIdx.x;
    float m0 = -INFINITY, m1 = -INFINITY;
    for (int n = bs[b]; n < be[b]; n++){
        const short2v hv = *(const short2v*)(h + (size_t)n*ldh + c);
        m0 = fmaxf(m0, b2f(hv[0]));
        m1 = fmaxf(m1, b2f(hv[1]));
    }
    float* gp = g + (size_t)b*ldg + gc0 + c;
    gp[0] = (m0 == -INFINITY) ? 0.f : m0;
    gp[1] = (m1 == -INFINITY) ? 0.f : m1;
}

// ================= row L2 normalize =================
__global__ __launch_bounds__(256)
void l2n_kernel(const float* __restrict__ in, float* __restrict__ outp,
                int cols, int ldi, int ldo)
{
    __shared__ float red[4];
    const int r = blockIdx.x;
    const int t = threadIdx.x;
    const float* ip = in + (size_t)r*ldi;
    float* op = outp + (size_t)r*ldo;
    float s = 0.f;
    for (int c=t; c<cols; c+=256){ float v = ip[c]; s += v*v; }
    #pragma unroll
    for (int o=32;o;o>>=1) s += __shfl_xor(s, o, 64);
    if ((t & 63) == 0) red[t>>6] = s;
    __syncthreads();
    float tot = red[0]+red[1]+red[2]+red[3];
    float inv = 1.0f / fmaxf(sqrtf(tot), 1e-12f);
    for (int c=t; c<cols; c+=256) op[c] = ip[c]*inv;
}

// ================= final 256->1 dot + sigmoid =================
__global__ __launch_bounds__(64)
void final_kernel(const float* __restrict__ f2, const float* __restrict__ w,
                  const float* __restrict__ b, float* __restrict__ outp)
{
    const int r = blockIdx.x;
    const int lane = threadIdx.x;
    const float* fp = f2 + (size_t)r*256;
    float s = 0.f;
    for (int c=lane; c<256; c+=64) s += fp[c]*w[c];
    #pragma unroll
    for (int o=32;o;o>>=1) s += __shfl_xor(s, o, 64);
    if (lane==0) outp[r] = 1.0f/(1.0f + expf(-(s + b[0])));
}

extern "C" void kernel_launch(void* const* d_in, const int* in_sizes, int n_in,
                              void* d_out, int out_size, void* d_ws, size_t ws_size,
                              hipStream_t stream)
{
    const float* x1  = (const float*)d_in[0];
    const int*   ei1 = (const int*)  d_in[1];
    const int*   bt1 = (const int*)  d_in[2];
    const float* x2  = (const float*)d_in[3];
    const int*   ei2 = (const int*)  d_in[4];
    const int*   bt2 = (const int*)  d_in[5];
    const float* cell= (const float*)d_in[6];
    const float* wq1=(const float*)d_in[7];  const float* bq1=(const float*)d_in[8];
    const float* wk1=(const float*)d_in[9];  const float* bk1=(const float*)d_in[10];
    const float* wv1=(const float*)d_in[11]; const float* bv1=(const float*)d_in[12];
    const float* ws1=(const float*)d_in[13]; const float* bs1=(const float*)d_in[14];
    const float* wq2=(const float*)d_in[15]; const float* bq2=(const float*)d_in[16];
    const float* wk2=(const float*)d_in[17]; const float* bk2=(const float*)d_in[18];
    const float* wv2=(const float*)d_in[19]; const float* bv2=(const float*)d_in[20];
    const float* ws2=(const float*)d_in[21]; const float* bs2=(const float*)d_in[22];
    const float* wg1=(const float*)d_in[23]; const float* bg1=(const float*)d_in[24];
    const float* wg2=(const float*)d_in[25]; const float* bg2=(const float*)d_in[26];
    const float* wr1=(const float*)d_in[27]; const float* br1=(const float*)d_in[28];
    const float* wr2=(const float*)d_in[29]; const float* br2=(const float*)d_in[30];
    const float* wr3=(const float*)d_in[31]; const float* br3=(const float*)d_in[32];
    const float* wf1=(const float*)d_in[33]; const float* bf1=(const float*)d_in[34];
    const float* gbn1=(const float*)d_in[35];const float* bbn1=(const float*)d_in[36];
    const float* wf2=(const float*)d_in[37]; const float* bf2=(const float*)d_in[38];
    const float* gbn2=(const float*)d_in[39];const float* bbn2=(const float*)d_in[40];
    const float* wf3=(const float*)d_in[41]; const float* bf3=(const float*)d_in[42];
    float* outp = (float*)d_out;
    (void)in_sizes; (void)n_in; (void)out_size; (void)ws_size;

    const float BNS = 1.0f / sqrtf(1.0f + 1e-5f);

    // ---- workspace arena (~103 MB peak; pbuf aliases dead qkvs) ----
    char* basep = (char*)d_ws;
    size_t off = 0;
    auto alloc = [&](size_t nbytes)->char* {
        char* p = basep + off;
        off += (nbytes + 255) & ~(size_t)255;
        return p;
    };
    float* xc   = (float*)alloc((size_t)BB*384*4);
    int* rowptr = (int*)  alloc((size_t)(NN+1)*4);
    int* cnt    = (int*)  alloc((size_t)NN*4);
    int* se     = (int*)  alloc((size_t)EE*4);
    int* bstart = (int*)  alloc((size_t)BB*4);
    int* bend   = (int*)  alloc((size_t)BB*4);
    float* g    = (float*)alloc((size_t)BB*1024*4);
    float* gh   = (float*)alloc((size_t)BB*512*4);
    float* cn   = (float*)alloc((size_t)BB*954*4);
    float* c1   = (float*)alloc((size_t)BB*512*4);
    float* c2   = (float*)alloc((size_t)BB*256*4);
    float* f1   = (float*)alloc((size_t)BB*512*4);
    float* f2   = (float*)alloc((size_t)BB*256*4);
    bf16* W1t   = (bf16*) alloc((size_t)1024*96*2);
    float* b1c  = (float*)alloc((size_t)1024*4);
    bf16* W2t   = (bf16*) alloc((size_t)2*2048*256*2);
    float* b2c  = (float*)alloc((size_t)4096*4);
    bf16* xa    = (bf16*) alloc((size_t)NN*96*2);
    bf16* h1    = (bf16*) alloc((size_t)NN*256*2);
    bf16* h2h   = (bf16*) alloc((size_t)NN*512*2);
    bf16* qkvs  = (bf16*) alloc((size_t)NN*2048*2);
    float* pbuf = (float*)qkvs;   // split-K partials: 8 MB << 64 MB, qkvs dead then

    // ---- one-time weight repack (per launch) ----
    prep_w1_kernel<<<(1024*96)/256,256,0,stream>>>(wq1,wk1,wv1,ws1, W1t);
    prep_b1_kernel<<<4,256,0,stream>>>(bq1,bk1,bv1,bs1, b1c);
    prep_w2_kernel<<<(2*2048*256)/256,256,0,stream>>>(wq2,wk2,wv2,ws2, W2t);
    prep_b2_kernel<<<16,256,0,stream>>>(bq2,bk2,bv2,bs2, b2c);

    for (int br=0; br<2; br++){
        const float* x  = br ? x2  : x1;
        const int*   ei = br ? ei2 : ei1;
        const int*   bt = br ? bt2 : bt1;
        float* gout = xc + br*128;

        // CSR of incoming edges + per-graph node ranges
        hipMemsetAsync(cnt, 0, (size_t)NN*4, stream);
        hist_kernel<<<EE/256,256,0,stream>>>(ei, cnt);
        scan_kernel<<<1,1024,0,stream>>>(cnt, rowptr);
        hipMemsetAsync(cnt, 0, (size_t)NN*4, stream);
        scatter_kernel<<<EE/256,256,0,stream>>>(ei, rowptr, cnt, se);
        hipMemsetAsync(bstart, 0, (size_t)BB*4, stream);
        hipMemsetAsync(bend,   0, (size_t)BB*4, stream);
        range_kernel<<<NN/256,256,0,stream>>>(bt, bstart, bend);

        // ---- layer 1: fused q|k|v|s GEMM [NN,96]x[96,1024] ----
        cvt_x_kernel<<<(NN*96)/256,256,0,stream>>>(x, xa);
        mfma_gemm<<<dim3(1024/128, NN/128),256,0,stream>>>(xa,96, W1t,96, b1c, qkvs,1024, 96);
        attn_kernel<128><<<NN*2/4,256,0,stream>>>(qkvs,1024, 0,256,512,768, 2, h1,256,0, rowptr,se);

        // ---- layer 2: per head fused q|k|v|s GEMM [NN,256]x[256,2048] ----
        for (int h=0; h<2; h++){
            mfma_gemm<<<dim3(2048/128, NN/128),256,0,stream>>>(h1,256, W2t + (size_t)h*2048*256,256,
                                                               b2c + h*2048, qkvs,2048, 256);
            attn_kernel<512><<<NN/4,256,0,stream>>>(qkvs,2048, 0,512,1024,1536, 1, h2h,512,0, rowptr,se);
            pool_kernel<<<BB,256,0,stream>>>(h2h,512, bstart,bend, g,1024, h*512);
        }

        // ---- graph head (split-K fp32): 1024 -> 512 lrelu -> 128, then l2n ----
        skgemm_partial<<<dim3(8,8,8),256,0,stream>>>(g,1024, wg1,512, pbuf, BB,512,1024,128);
        skgemm_reduce<1><<<(BB*512)/256,256,0,stream>>>(pbuf, bg1, nullptr,nullptr,1.f, gh,512, BB,512,8);
        skgemm_partial<<<dim3(2,8,8),256,0,stream>>>(gh,512, wg2,128, pbuf, BB,128,512,64);
        skgemm_reduce<0><<<(BB*128)/256,256,0,stream>>>(pbuf, bg2, nullptr,nullptr,1.f, gout,384, BB,128,8);
        l2n_kernel<<<BB,256,0,stream>>>(gout, gout, 128, 384, 384);
    }

    // ---- cell branch (split-K fp32) ----
    l2n_kernel<<<BB,256,0,stream>>>(cell, cn, 954, 954, 954);
    skgemm_partial<<<dim3(8,8,8),256,0,stream>>>(cn,954, wr1,512, pbuf, BB,512,954,120);
    skgemm_reduce<1><<<(BB*512)/256,256,0,stream>>>(pbuf, br1, nullptr,nullptr,1.f, c1,512, BB,512,8);
    skgemm_partial<<<dim3(4,8,8),256,0,stream>>>(c1,512, wr2,256, pbuf, BB,256,512,64);
    skgemm_reduce<1><<<(BB*256)/256,256,0,stream>>>(pbuf, br2, nullptr,nullptr,1.f, c2,256, BB,256,8);
    skgemm_partial<<<dim3(2,8,8),256,0,stream>>>(c2,256, wr3,128, pbuf, BB,128,256,32);
    skgemm_reduce<0><<<(BB*128)/256,256,0,stream>>>(pbuf, br3, nullptr,nullptr,1.f, xc+256,384, BB,128,8);

    // ---- head MLP (split-K fp32 + fused BN) ----
    l2n_kernel<<<BB,256,0,stream>>>(xc, xc, 384, 384, 384);
    skgemm_partial<<<dim3(8,8,8),256,0,stream>>>(xc,384, wf1,512, pbuf, BB,512,384,48);
    skgemm_reduce<2><<<(BB*512)/256,256,0,stream>>>(pbuf, bf1, gbn1,bbn1,BNS, f1,512, BB,512,8);
    skgemm_partial<<<dim3(4,8,8),256,0,stream>>>(f1,512, wf2,256, pbuf, BB,256,512,64);
    skgemm_reduce<2><<<(BB*256)/256,256,0,stream>>>(pbuf, bf2, gbn2,bbn2,BNS, f2,256, BB,256,8);
    final_kernel<<<BB,64,0,stream>>>(f2, wf3, bf3, outp);
}

// Round 5
// 798.090 us; speedup vs baseline: 3.3874x; 1.0040x over previous
//
#include <hip/hip_runtime.h>
#include <hip/hip_bf16.h>
#include <math.h>
#include <stdint.h>

typedef __hip_bfloat16 bf16;

#define NN 16384
#define EE 65536
#define BB 512

typedef __attribute__((ext_vector_type(8))) short short8;
typedef __attribute__((ext_vector_type(4))) float floatx4;

__device__ __forceinline__ float lrelu_f(float x){ return x >= 0.f ? x : 0.01f*x; }

__device__ __forceinline__ float b2f(short s){
    unsigned int u = ((unsigned int)(unsigned short)s) << 16;
    float f; __builtin_memcpy(&f, &u, 4); return f;
}
__device__ __forceinline__ short f2b(float f){
    bf16 b = (bf16)f;
    short s; __builtin_memcpy(&s, &b, 2); return s;
}

// async 16B global->LDS. LDS dest is wave-uniform base; lane i lands at base+16*i.
__device__ __forceinline__ void gl2lds16(const void* g, void* l){
    __builtin_amdgcn_global_load_lds(
        (__attribute__((address_space(1))) unsigned int*)(uintptr_t)g,
        (__attribute__((address_space(3))) unsigned int*)(uintptr_t)l, 16, 0, 0);
}

// ================= MFMA bf16 GEMM: C[m,n] = A[m,:K] @ W[:,n] + bias[n] =================
__global__ __launch_bounds__(256)
void mfma_gemm(const bf16* __restrict__ A, int lda,
               const bf16* __restrict__ Bt, int ldb,
               const float* __restrict__ bias,
               bf16* __restrict__ C, int ldc, int K)
{
    __shared__ bf16 As[128*32];   // As[r][k]
    __shared__ bf16 Bs[128*32];   // Bs[n][k]
    const int tid  = threadIdx.x;
    const int wave = tid >> 6;
    const int lane = tid & 63;
    const int wm = (wave & 1) * 64;
    const int wn = (wave >> 1) * 64;
    const int m0 = blockIdx.y * 128;
    const int n0 = blockIdx.x * 128;

    const int srow = lane >> 2;
    const int scol = (lane & 3) * 8;
    const int arow = lane & 15;
    const int aq   = (lane >> 4) * 8;

    floatx4 acc[4][4];
    #pragma unroll
    for (int i=0;i<4;i++)
        #pragma unroll
        for (int j=0;j<4;j++) acc[i][j] = (floatx4){0.f,0.f,0.f,0.f};

    for (int k0 = 0; k0 < K; k0 += 32) {
        #pragma unroll
        for (int i = 0; i < 2; i++) {
            const int chunk = wave*2 + i;
            const int r = chunk*16 + srow;
            gl2lds16(A  + (size_t)(m0 + r)*lda + k0 + scol, As + chunk*512);
            gl2lds16(Bt + (size_t)(n0 + r)*ldb + k0 + scol, Bs + chunk*512);
        }
        __syncthreads();
        short8 af[4], bf_[4];
        #pragma unroll
        for (int i=0;i<4;i++) af[i]  = *(const short8*)(As + (wm + i*16 + arow)*32 + aq);
        #pragma unroll
        for (int j=0;j<4;j++) bf_[j] = *(const short8*)(Bs + (wn + j*16 + arow)*32 + aq);
        #pragma unroll
        for (int i=0;i<4;i++)
            #pragma unroll
            for (int j=0;j<4;j++)
                acc[i][j] = __builtin_amdgcn_mfma_f32_16x16x32_bf16(af[i], bf_[j], acc[i][j], 0,0,0);
        __syncthreads();
    }
    const int crow = (lane >> 4) * 4;
    const int ccol = lane & 15;
    #pragma unroll
    for (int j=0;j<4;j++){
        const int n = n0 + wn + j*16 + ccol;
        const float bs = bias[n];
        #pragma unroll
        for (int i=0;i<4;i++){
            const int m = m0 + wm + i*16 + crow;
            #pragma unroll
            for (int r=0;r<4;r++)
                C[(size_t)(m + r)*ldc + n] = (bf16)(acc[i][j][r] + bs);
        }
    }
}

// ================= weight/bias/activation prep =================
__global__ void cvt_x_kernel(const float* __restrict__ x, bf16* __restrict__ xa){
    int i = blockIdx.x*256 + threadIdx.x;
    int r = i / 96, c = i - r*96;
    xa[i] = (c < 78) ? (bf16)x[(size_t)r*78 + c] : (bf16)0.f;
}

__global__ void prep_w1_kernel(const float* __restrict__ wq, const float* __restrict__ wk,
                               const float* __restrict__ wv, const float* __restrict__ ws,
                               bf16* __restrict__ W1t){
    int i = blockIdx.x*256 + threadIdx.x;          // 1024*96
    int n = i / 96, k = i - n*96;
    const float* w = (n<256)?wq:(n<512)?wk:(n<768)?wv:ws;
    int col = n & 255;
    W1t[i] = (k < 78) ? (bf16)w[(size_t)k*256 + col] : (bf16)0.f;
}

__global__ void prep_b1_kernel(const float* __restrict__ bq, const float* __restrict__ bk,
                               const float* __restrict__ bv, const float* __restrict__ bs,
                               float* __restrict__ b1c){
    int i = blockIdx.x*256 + threadIdx.x;
    if (i >= 1024) return;
    const float* b = (i<256)?bq:(i<512)?bk:(i<768)?bv:bs;
    b1c[i] = b[i & 255];
}

__global__ void prep_w2_kernel(const float* __restrict__ wq, const float* __restrict__ wk,
                               const float* __restrict__ wv, const float* __restrict__ ws,
                               bf16* __restrict__ W2t){
    int i = blockIdx.x*256 + threadIdx.x;          // 2*2048*256
    int k = i & 255;
    int j = (i >> 8) & 2047;
    int h = i >> 19;
    const float* w = (j<512)?wq:(j<1024)?wk:(j<1536)?wv:ws;
    int col = h*512 + (j & 511);
    W2t[i] = (bf16)w[(size_t)k*1024 + col];
}

__global__ void prep_b2_kernel(const float* __restrict__ bq, const float* __restrict__ bk,
                               const float* __restrict__ bv, const float* __restrict__ bs,
                               float* __restrict__ b2c){
    int i = blockIdx.x*256 + threadIdx.x;
    if (i >= 4096) return;
    int j = i & 2047, h = i >> 11;
    const float* b = (j<512)?bq:(j<1024)?bk:(j<1536)?bv:bs;
    b2c[i] = b[h*512 + (j & 511)];
}

// ================= split-K fp32 GEMM for B=512 MLP heads =================
__global__ __launch_bounds__(256)
void skgemm_partial(const float* __restrict__ A, int lda,
                    const float* __restrict__ W, int ldw,
                    float* __restrict__ P,
                    int M, int N, int K, int Kc)
{
    __shared__ float As[16][68];
    __shared__ float Bs[16][68];
    const int tid = threadIdx.x;
    const int tx = tid & 15;
    const int ty = tid >> 4;
    const int m0 = blockIdx.y * 64;
    const int n0 = blockIdx.x * 64;
    const int s  = blockIdx.z;
    const int kb = s * Kc;
    const int ke = min(K, kb + Kc);
    float acc[4][4];
    #pragma unroll
    for (int i=0;i<4;i++)
        #pragma unroll
        for (int j=0;j<4;j++) acc[i][j]=0.f;

    for (int k0=kb; k0<ke; k0+=16) {
        #pragma unroll
        for (int i=0;i<4;i++){
            int idx = tid + i*256;
            int r = idx >> 4, c = idx & 15;
            int kk = k0 + c;
            As[c][r] = (kk < ke) ? A[(size_t)(m0+r)*lda + kk] : 0.f;
        }
        #pragma unroll
        for (int i=0;i<4;i++){
            int idx = tid + i*256;
            int r = idx >> 6, c = idx & 63;
            int kk = k0 + r;
            Bs[r][c] = (kk < ke) ? W[(size_t)kk*ldw + n0 + c] : 0.f;
        }
        __syncthreads();
        #pragma unroll
        for (int kk=0;kk<16;kk++){
            float a[4], b[4];
            #pragma unroll
            for (int i=0;i<4;i++) a[i] = As[kk][ty*4+i];
            #pragma unroll
            for (int j=0;j<4;j++) b[j] = Bs[kk][tx*4+j];
            #pragma unroll
            for (int i=0;i<4;i++)
                #pragma unroll
                for (int j=0;j<4;j++) acc[i][j] += a[i]*b[j];
        }
        __syncthreads();
    }
    float* Pp = P + (size_t)s*M*N;
    #pragma unroll
    for (int i=0;i<4;i++){
        int m = m0 + ty*4 + i;
        #pragma unroll
        for (int j=0;j<4;j++){
            int n = n0 + tx*4 + j;
            Pp[(size_t)m*N + n] = acc[i][j];
        }
    }
}

template<int ACT>
__global__ __launch_bounds__(256)
void skgemm_reduce(const float* __restrict__ P,
                   const float* __restrict__ bias,
                   const float* __restrict__ gamma,
                   const float* __restrict__ beta,
                   float bnscale,
                   float* __restrict__ C, int ldc,
                   int M, int N, int S)
{
    int i = blockIdx.x*256 + threadIdx.x;
    if (i >= M*N) return;
    int m = i / N, n = i - m*N;
    float v = 0.f;
    for (int s=0; s<S; s++) v += P[(size_t)s*M*N + i];
    v += bias[n];
    if (ACT==1) v = lrelu_f(v);
    if (ACT==2) { v = v*bnscale*gamma[n] + beta[n]; v = lrelu_f(v); }
    C[(size_t)m*ldc + n] = v;
}

// ================= CSR build =================
__global__ void hist_kernel(const int* __restrict__ ei, int* __restrict__ cnt){
    int e = blockIdx.x*256 + threadIdx.x;
    atomicAdd(&cnt[ei[EE + e]], 1);
}

__global__ __launch_bounds__(1024)
void scan_kernel(const int* __restrict__ hist, int* __restrict__ rowptr){
    __shared__ int sums[1024];
    const int t = threadIdx.x;
    const int base = t*16;
    int loc[16]; int s = 0;
    #pragma unroll
    for (int i=0;i<16;i++){ loc[i]=s; s += hist[base+i]; }
    sums[t] = s; __syncthreads();
    for (int o=1;o<1024;o<<=1){
        int v = (t>=o) ? sums[t-o] : 0;
        __syncthreads();
        sums[t] += v;
        __syncthreads();
    }
    int pref = (t>0) ? sums[t-1] : 0;
    #pragma unroll
    for (int i=0;i<16;i++) rowptr[base+i] = pref + loc[i];
    if (t==1023) rowptr[NN] = sums[1023];
}

// stores SOURCE NODE ID directly
__global__ void scatter_kernel(const int* __restrict__ ei, const int* __restrict__ rowptr,
                               int* __restrict__ cnt, int* __restrict__ srcs){
    int e = blockIdx.x*256 + threadIdx.x;
    int d = ei[EE + e];
    int pos = rowptr[d] + atomicAdd(&cnt[d], 1);
    srcs[pos] = ei[e];
}

__global__ void range_kernel(const int* __restrict__ bt, int* __restrict__ bs, int* __restrict__ be){
    int n = blockIdx.x*256 + threadIdx.x;
    int b = bt[n];
    if (n==0     || bt[n-1]!=b) bs[b] = n;
    if (n==NN-1  || bt[n+1]!=b) be[b] = n+1;
}

// ================= attention: one wave per (dst node, head) ==========================
// Chunked: 4 edges per iteration. srcs broadcast via shfl; 8 gathers in flight;
// 4 interleaved shuffle reductions; one online-softmax update per chunk; exp2 domain.
template<int D>
__global__ __launch_bounds__(256)
void attn_kernel(const bf16* __restrict__ qkvs, int ld, int qo, int ko, int vo, int so, int H,
                 bf16* __restrict__ hout, int ldo, int oo,
                 const int* __restrict__ rowptr, const int* __restrict__ srcs)
{
    constexpr int PER = D / 64;
    typedef __attribute__((ext_vector_type(PER))) short shortP;
    const int lane = threadIdx.x & 63;
    const int gw = blockIdx.x * 4 + (threadIdx.x >> 6);
    const int n = gw / H;
    const int h = gw - n*H;
    const float qscale = rsqrtf((float)D) * 1.44269504f;  // fold log2(e): exp2 domain
    const int hd = h*D + lane*PER;

    const shortP qv = *(const shortP*)(qkvs + (size_t)n*ld + qo + hd);
    float qr[PER];
    #pragma unroll
    for (int i=0;i<PER;i++) qr[i] = b2f(qv[i]) * qscale;

    const int e0 = rowptr[n], e1 = rowptr[n+1];
    float m = -INFINITY, z = 0.f;
    float acc[PER];
    #pragma unroll
    for (int i=0;i<PER;i++) acc[i] = 0.f;

    for (int base = e0; base < e1; base += 4){
        const int cnt = min(4, e1 - base);
        // lane-parallel src fetch, clamped; broadcast 4 values to whole wave
        int sl = srcs[min(base + (lane & 3), e1 - 1)];
        int src[4];
        #pragma unroll
        for (int j=0;j<4;j++) src[j] = __shfl(sl, j, 64);

        // issue all k and v gathers up front (8 independent loads in flight)
        shortP kv[4], vv[4];
        #pragma unroll
        for (int j=0;j<4;j++){
            if (j < cnt){
                const bf16* rp = qkvs + (size_t)src[j]*ld;
                kv[j] = *(const shortP*)(rp + ko + hd);
                vv[j] = *(const shortP*)(rp + vo + hd);
            }
        }
        // 4 dots, reductions interleaved (independent dependency chains)
        float dt[4];
        #pragma unroll
        for (int j=0;j<4;j++){
            float d = 0.f;
            if (j < cnt){
                #pragma unroll
                for (int i=0;i<PER;i++) d += qr[i]*b2f(kv[j][i]);
            }
            dt[j] = d;
        }
        #pragma unroll
        for (int o=32;o;o>>=1){
            #pragma unroll
            for (int j=0;j<4;j++) dt[j] += __shfl_xor(dt[j], o, 64);
        }
        // chunk max then single rescale
        float cm = -INFINITY;
        #pragma unroll
        for (int j=0;j<4;j++) if (j < cnt) cm = fmaxf(cm, dt[j]);
        const float mn = fmaxf(m, cm);
        const float cs = exp2f(m - mn);     // 0 on first chunk (m=-inf)
        z *= cs;
        #pragma unroll
        for (int i=0;i<PER;i++) acc[i] *= cs;
        #pragma unroll
        for (int j=0;j<4;j++){
            if (j < cnt){
                const float w = exp2f(dt[j] - mn);
                z += w;
                #pragma unroll
                for (int i=0;i<PER;i++) acc[i] += w*b2f(vv[j][i]);
            }
        }
        m = mn;
    }
    const float invz = 1.0f/(z + 1e-16f);
    const shortP sv = *(const shortP*)(qkvs + (size_t)n*ld + so + hd);
    shortP ov;
    #pragma unroll
    for (int i=0;i<PER;i++) ov[i] = f2b(lrelu_f(b2f(sv[i]) + acc[i]*invz));
    *(shortP*)(hout + (size_t)n*ldo + oo + hd) = ov;
}

// ================= segment-max pool (512 cols fixed, one block per graph) =================
__global__ __launch_bounds__(256)
void pool_kernel(const bf16* __restrict__ h, int ldh,
                 const int* __restrict__ bs, const int* __restrict__ be,
                 float* __restrict__ g, int ldg, int gc0)
{
    typedef __attribute__((ext_vector_type(2))) short short2v;
    const int c = threadIdx.x * 2;          // 512 cols
    const int b = blockIdx.x;
    float m0 = -INFINITY, m1 = -INFINITY;
    for (int n = bs[b]; n < be[b]; n++){
        const short2v hv = *(const short2v*)(h + (size_t)n*ldh + c);
        m0 = fmaxf(m0, b2f(hv[0]));
        m1 = fmaxf(m1, b2f(hv[1]));
    }
    float* gp = g + (size_t)b*ldg + gc0 + c;
    gp[0] = (m0 == -INFINITY) ? 0.f : m0;
    gp[1] = (m1 == -INFINITY) ? 0.f : m1;
}

// ================= row L2 normalize =================
__global__ __launch_bounds__(256)
void l2n_kernel(const float* __restrict__ in, float* __restrict__ outp,
                int cols, int ldi, int ldo)
{
    __shared__ float red[4];
    const int r = blockIdx.x;
    const int t = threadIdx.x;
    const float* ip = in + (size_t)r*ldi;
    float* op = outp + (size_t)r*ldo;
    float s = 0.f;
    for (int c=t; c<cols; c+=256){ float v = ip[c]; s += v*v; }
    #pragma unroll
    for (int o=32;o;o>>=1) s += __shfl_xor(s, o, 64);
    if ((t & 63) == 0) red[t>>6] = s;
    __syncthreads();
    float tot = red[0]+red[1]+red[2]+red[3];
    float inv = 1.0f / fmaxf(sqrtf(tot), 1e-12f);
    for (int c=t; c<cols; c+=256) op[c] = ip[c]*inv;
}

// ================= final 256->1 dot + sigmoid =================
__global__ __launch_bounds__(64)
void final_kernel(const float* __restrict__ f2, const float* __restrict__ w,
                  const float* __restrict__ b, float* __restrict__ outp)
{
    const int r = blockIdx.x;
    const int lane = threadIdx.x;
    const float* fp = f2 + (size_t)r*256;
    float s = 0.f;
    for (int c=lane; c<256; c+=64) s += fp[c]*w[c];
    #pragma unroll
    for (int o=32;o;o>>=1) s += __shfl_xor(s, o, 64);
    if (lane==0) outp[r] = 1.0f/(1.0f + expf(-(s + b[0])));
}

extern "C" void kernel_launch(void* const* d_in, const int* in_sizes, int n_in,
                              void* d_out, int out_size, void* d_ws, size_t ws_size,
                              hipStream_t stream)
{
    const float* x1  = (const float*)d_in[0];
    const int*   ei1 = (const int*)  d_in[1];
    const int*   bt1 = (const int*)  d_in[2];
    const float* x2  = (const float*)d_in[3];
    const int*   ei2 = (const int*)  d_in[4];
    const int*   bt2 = (const int*)  d_in[5];
    const float* cell= (const float*)d_in[6];
    const float* wq1=(const float*)d_in[7];  const float* bq1=(const float*)d_in[8];
    const float* wk1=(const float*)d_in[9];  const float* bk1=(const float*)d_in[10];
    const float* wv1=(const float*)d_in[11]; const float* bv1=(const float*)d_in[12];
    const float* ws1=(const float*)d_in[13]; const float* bs1=(const float*)d_in[14];
    const float* wq2=(const float*)d_in[15]; const float* bq2=(const float*)d_in[16];
    const float* wk2=(const float*)d_in[17]; const float* bk2=(const float*)d_in[18];
    const float* wv2=(const float*)d_in[19]; const float* bv2=(const float*)d_in[20];
    const float* ws2=(const float*)d_in[21]; const float* bs2=(const float*)d_in[22];
    const float* wg1=(const float*)d_in[23]; const float* bg1=(const float*)d_in[24];
    const float* wg2=(const float*)d_in[25]; const float* bg2=(const float*)d_in[26];
    const float* wr1=(const float*)d_in[27]; const float* br1=(const float*)d_in[28];
    const float* wr2=(const float*)d_in[29]; const float* br2=(const float*)d_in[30];
    const float* wr3=(const float*)d_in[31]; const float* br3=(const float*)d_in[32];
    const float* wf1=(const float*)d_in[33]; const float* bf1=(const float*)d_in[34];
    const float* gbn1=(const float*)d_in[35];const float* bbn1=(const float*)d_in[36];
    const float* wf2=(const float*)d_in[37]; const float* bf2=(const float*)d_in[38];
    const float* gbn2=(const float*)d_in[39];const float* bbn2=(const float*)d_in[40];
    const float* wf3=(const float*)d_in[41]; const float* bf3=(const float*)d_in[42];
    float* outp = (float*)d_out;
    (void)in_sizes; (void)n_in; (void)out_size; (void)ws_size;

    const float BNS = 1.0f / sqrtf(1.0f + 1e-5f);

    // ---- workspace arena (~103 MB peak; pbuf aliases dead qkvs) ----
    char* basep = (char*)d_ws;
    size_t off = 0;
    auto alloc = [&](size_t nbytes)->char* {
        char* p = basep + off;
        off += (nbytes + 255) & ~(size_t)255;
        return p;
    };
    float* xc   = (float*)alloc((size_t)BB*384*4);
    int* rowptr = (int*)  alloc((size_t)(NN+1)*4);
    int* cnt    = (int*)  alloc((size_t)NN*4);
    int* se     = (int*)  alloc((size_t)EE*4);
    int* bstart = (int*)  alloc((size_t)BB*4);
    int* bend   = (int*)  alloc((size_t)BB*4);
    float* g    = (float*)alloc((size_t)BB*1024*4);
    float* gh   = (float*)alloc((size_t)BB*512*4);
    float* cn   = (float*)alloc((size_t)BB*954*4);
    float* c1   = (float*)alloc((size_t)BB*512*4);
    float* c2   = (float*)alloc((size_t)BB*256*4);
    float* f1   = (float*)alloc((size_t)BB*512*4);
    float* f2   = (float*)alloc((size_t)BB*256*4);
    bf16* W1t   = (bf16*) alloc((size_t)1024*96*2);
    float* b1c  = (float*)alloc((size_t)1024*4);
    bf16* W2t   = (bf16*) alloc((size_t)2*2048*256*2);
    float* b2c  = (float*)alloc((size_t)4096*4);
    bf16* xa    = (bf16*) alloc((size_t)NN*96*2);
    bf16* h1    = (bf16*) alloc((size_t)NN*256*2);
    bf16* h2h   = (bf16*) alloc((size_t)NN*512*2);
    bf16* qkvs  = (bf16*) alloc((size_t)NN*2048*2);
    float* pbuf = (float*)qkvs;   // split-K partials: 8 MB << 64 MB, qkvs dead then

    // ---- one-time weight repack (per launch) ----
    prep_w1_kernel<<<(1024*96)/256,256,0,stream>>>(wq1,wk1,wv1,ws1, W1t);
    prep_b1_kernel<<<4,256,0,stream>>>(bq1,bk1,bv1,bs1, b1c);
    prep_w2_kernel<<<(2*2048*256)/256,256,0,stream>>>(wq2,wk2,wv2,ws2, W2t);
    prep_b2_kernel<<<16,256,0,stream>>>(bq2,bk2,bv2,bs2, b2c);

    for (int br=0; br<2; br++){
        const float* x  = br ? x2  : x1;
        const int*   ei = br ? ei2 : ei1;
        const int*   bt = br ? bt2 : bt1;
        float* gout = xc + br*128;

        // CSR of incoming edges + per-graph node ranges
        hipMemsetAsync(cnt, 0, (size_t)NN*4, stream);
        hist_kernel<<<EE/256,256,0,stream>>>(ei, cnt);
        scan_kernel<<<1,1024,0,stream>>>(cnt, rowptr);
        hipMemsetAsync(cnt, 0, (size_t)NN*4, stream);
        scatter_kernel<<<EE/256,256,0,stream>>>(ei, rowptr, cnt, se);
        hipMemsetAsync(bstart, 0, (size_t)BB*4, stream);
        hipMemsetAsync(bend,   0, (size_t)BB*4, stream);
        range_kernel<<<NN/256,256,0,stream>>>(bt, bstart, bend);

        // ---- layer 1: fused q|k|v|s GEMM [NN,96]x[96,1024] ----
        cvt_x_kernel<<<(NN*96)/256,256,0,stream>>>(x, xa);
        mfma_gemm<<<dim3(1024/128, NN/128),256,0,stream>>>(xa,96, W1t,96, b1c, qkvs,1024, 96);
        attn_kernel<128><<<NN*2/4,256,0,stream>>>(qkvs,1024, 0,256,512,768, 2, h1,256,0, rowptr,se);

        // ---- layer 2: per head fused q|k|v|s GEMM [NN,256]x[256,2048] ----
        for (int h=0; h<2; h++){
            mfma_gemm<<<dim3(2048/128, NN/128),256,0,stream>>>(h1,256, W2t + (size_t)h*2048*256,256,
                                                               b2c + h*2048, qkvs,2048, 256);
            attn_kernel<512><<<NN/4,256,0,stream>>>(qkvs,2048, 0,512,1024,1536, 1, h2h,512,0, rowptr,se);
            pool_kernel<<<BB,256,0,stream>>>(h2h,512, bstart,bend, g,1024, h*512);
        }

        // ---- graph head (split-K fp32): 1024 -> 512 lrelu -> 128, then l2n ----
        skgemm_partial<<<dim3(8,8,8),256,0,stream>>>(g,1024, wg1,512, pbuf, BB,512,1024,128);
        skgemm_reduce<1><<<(BB*512)/256,256,0,stream>>>(pbuf, bg1, nullptr,nullptr,1.f, gh,512, BB,512,8);
        skgemm_partial<<<dim3(2,8,8),256,0,stream>>>(gh,512, wg2,128, pbuf, BB,128,512,64);
        skgemm_reduce<0><<<(BB*128)/256,256,0,stream>>>(pbuf, bg2, nullptr,nullptr,1.f, gout,384, BB,128,8);
        l2n_kernel<<<BB,256,0,stream>>>(gout, gout, 128, 384, 384);
    }

    // ---- cell branch (split-K fp32) ----
    l2n_kernel<<<BB,256,0,stream>>>(cell, cn, 954, 954, 954);
    skgemm_partial<<<dim3(8,8,8),256,0,stream>>>(cn,954, wr1,512, pbuf, BB,512,954,120);
    skgemm_reduce<1><<<(BB*512)/256,256,0,stream>>>(pbuf, br1, nullptr,nullptr,1.f, c1,512, BB,512,8);
    skgemm_partial<<<dim3(4,8,8),256,0,stream>>>(c1,512, wr2,256, pbuf, BB,256,512,64);
    skgemm_reduce<1><<<(BB*256)/256,256,0,stream>>>(pbuf, br2, nullptr,nullptr,1.f, c2,256, BB,256,8);
    skgemm_partial<<<dim3(2,8,8),256,0,stream>>>(c2,256, wr3,128, pbuf, BB,128,256,32);
    skgemm_reduce<0><<<(BB*128)/256,256,0,stream>>>(pbuf, br3, nullptr,nullptr,1.f, xc+256,384, BB,128,8);

    // ---- head MLP (split-K fp32 + fused BN) ----
    l2n_kernel<<<BB,256,0,stream>>>(xc, xc, 384, 384, 384);
    skgemm_partial<<<dim3(8,8,8),256,0,stream>>>(xc,384, wf1,512, pbuf, BB,512,384,48);
    skgemm_reduce<2><<<(BB*512)/256,256,0,stream>>>(pbuf, bf1, gbn1,bbn1,BNS, f1,512, BB,512,8);
    skgemm_partial<<<dim3(4,8,8),256,0,stream>>>(f1,512, wf2,256, pbuf, BB,256,512,64);
    skgemm_reduce<2><<<(BB*256)/256,256,0,stream>>>(pbuf, bf2, gbn2,bbn2,BNS, f2,256, BB,256,8);
    final_kernel<<<BB,64,0,stream>>>(f2, wf3, bf3, outp);
}